// Round 1
// baseline (637.280 us; speedup 1.0000x reference)
//
#include <hip/hip_runtime.h>
#include <cstdint>
#include <cstddef>

#define B_ 2
#define T_ 2048
#define C_ 2048
#define H_ 16
#define HKV_ 8
#define D_ 128
#define M_ (B_*T_)          // 4096 tokens
#define NKV_ (HKV_*D_)      // 1024

typedef unsigned short u16;
typedef __bf16 bf16_t;
typedef bf16_t bf16x8 __attribute__((ext_vector_type(8)));
typedef float f32x4 __attribute__((ext_vector_type(4)));

__device__ __forceinline__ u16 f2bf(float f) {
  union { float fl; uint32_t u; } v; v.fl = f;
  uint32_t u = v.u;
  return (u16)((u + 0x7fffu + ((u >> 16) & 1u)) >> 16);  // RNE
}

__device__ __forceinline__ void gload_lds16(const void* g, void* l) {
  // async global->LDS, 16B/lane; LDS dest = wave-uniform base + lane*16
  __builtin_amdgcn_global_load_lds(
      (const __attribute__((address_space(1))) unsigned int*)g,
      (__attribute__((address_space(3))) unsigned int*)l, 16, 0, 0);
}

__device__ __forceinline__ f32x4 mfma16(bf16x8 a, bf16x8 b, f32x4 c) {
  return __builtin_amdgcn_mfma_f32_16x16x32_bf16(a, b, c, 0, 0, 0);
}

// ---------------- elementwise f32 -> bf16 ----------------
__global__ void cvt_bf16(const float* __restrict__ in, u16* __restrict__ out, int n4) {
  int i = blockIdx.x * blockDim.x + threadIdx.x;
  if (i >= n4) return;
  float4 f = reinterpret_cast<const float4*>(in)[i];
  ushort4 o;
  o.x = f2bf(f.x); o.y = f2bf(f.y); o.z = f2bf(f.z); o.w = f2bf(f.w);
  reinterpret_cast<ushort4*>(out)[i] = o;
}

// ------- tiled transpose+convert: W[K][N] f32 -> WT[N][K] bf16 -------
__global__ void wtrans(const float* __restrict__ w, u16* __restrict__ wt, int Kd, int Nd) {
  __shared__ float tile[64][65];
  int ntt = Nd >> 6;
  int nt = blockIdx.x % ntt, kt = blockIdx.x / ntt;
  int cc = threadIdx.x & 63, r0 = threadIdx.x >> 6;
#pragma unroll
  for (int i = 0; i < 16; i++) {
    int r = r0 + i*4;
    tile[r][cc] = w[(size_t)(kt*64 + r)*Nd + nt*64 + cc];
  }
  __syncthreads();
#pragma unroll
  for (int i = 0; i < 16; i++) {
    int r = r0 + i*4;
    wt[(size_t)(nt*64 + r)*Kd + kt*64 + cc] = f2bf(tile[cc][r]);
  }
}

// ---------------- RoPE cos/sin table [T][64] f32 ----------------
__global__ void rope_tab(float* __restrict__ cs, float* __restrict__ sn) {
  int idx = blockIdx.x * blockDim.x + threadIdx.x;
  if (idx >= T_*64) return;
  int i = idx & 63, t = idx >> 6;
  float inv = powf(10000.f, -(float)i / 64.f);
  float fr = (float)t * inv;
  cs[idx] = cosf(fr);
  sn[idx] = sinf(fr);
}

// ---- rope + reshape: src f32 [B*T, nh*D] -> dst bf16 [B, nh, T, D] ----
__global__ void rope_apply(const float* __restrict__ src, u16* __restrict__ dst,
                           const float* __restrict__ cs, const float* __restrict__ sn,
                           int nheads) {
  int idx = blockIdx.x * blockDim.x + threadIdx.x;
  if (idx >= B_*T_*nheads*64) return;
  int i = idx & 63;
  int hh = (idx >> 6) % nheads;
  int bt = (idx >> 6) / nheads;
  int t = bt % T_, b = bt / T_;
  size_t sbase = (size_t)bt * nheads * D_ + (size_t)hh * D_;
  size_t obase = ((size_t)(b*nheads + hh) * T_ + t) * D_;
  float x1 = src[sbase + i], x2 = src[sbase + 64 + i];
  float cv = cs[t*64 + i], sv = sn[t*64 + i];
  dst[obase + i]      = f2bf(x1*cv - x2*sv);
  dst[obase + 64 + i] = f2bf(x2*cv + x1*sv);
}

// -- V: f32 [B*T, HKV*D] -> bf16 Vt [B, HKV, D, T] (transposed per head) --
__global__ void vtrans(const float* __restrict__ v, u16* __restrict__ vt) {
  __shared__ float tile[64][65];
  int bid = blockIdx.x;
  int dt = bid & 1;
  int tt = (bid >> 1) & 31;
  int h  = (bid >> 6) & 7;
  int b  = bid >> 9;
  int cc = threadIdx.x & 63, r0 = threadIdx.x >> 6;
#pragma unroll
  for (int i = 0; i < 16; i++) {
    int r = r0 + i*4;
    tile[r][cc] = v[(size_t)(b*T_ + tt*64 + r)*NKV_ + h*D_ + dt*64 + cc];
  }
  __syncthreads();
#pragma unroll
  for (int i = 0; i < 16; i++) {
    int r = r0 + i*4;  // d index within tile
    vt[((size_t)(b*HKV_ + h)*D_ + dt*64 + r)*T_ + tt*64 + cc] = f2bf(tile[cc][r]);
  }
}

// ---------------- GEMM: C[M][N] f32 = A[M][K] bf16 * Bt[N][K] bf16 ----------------
#define BM 128
#define BN 128
#define BK 64

__global__ __launch_bounds__(256, 2)
void gemm_bt(const u16* __restrict__ A, const u16* __restrict__ Bt,
             float* __restrict__ Cm, int Md, int Nd, int Kd) {
  __shared__ u16 sA[BM * BK];   // [128][64]
  __shared__ u16 sB[BN * BK];   // [128][64]
  const int tid = threadIdx.x;
  const int wave = tid >> 6, lane = tid & 63;
  const int g = lane >> 4, c = lane & 15;
  const int nbn = Nd / BN;
  const int bm = blockIdx.x / nbn, bn = blockIdx.x % nbn;
  const int m0 = bm * BM, n0 = bn * BN;
  const int wm = (wave >> 1) * 64, wn = (wave & 1) * 64;
  const int srow = lane >> 3, skcol = (lane & 7) * 8;

  f32x4 acc[4][4] = {};

  for (int k0 = 0; k0 < Kd; k0 += BK) {
    __syncthreads();
#pragma unroll
    for (int i = 0; i < 4; i++) {
      int chunk = i*4 + wave;              // wave-uniform
      int row = chunk*8 + srow;
      gload_lds16(A  + (size_t)(m0 + row)*Kd + k0 + skcol, &sA[chunk*512]);
      gload_lds16(Bt + (size_t)(n0 + row)*Kd + k0 + skcol, &sB[chunk*512]);
    }
    __syncthreads();
#pragma unroll
    for (int ks = 0; ks < 2; ks++) {
      bf16x8 af[4], bb[4];
#pragma unroll
      for (int mi = 0; mi < 4; mi++)
        af[mi] = *reinterpret_cast<const bf16x8*>(&sA[(wm + mi*16 + c)*BK + ks*32 + g*8]);
#pragma unroll
      for (int ni = 0; ni < 4; ni++)
        bb[ni] = *reinterpret_cast<const bf16x8*>(&sB[(wn + ni*16 + c)*BK + ks*32 + g*8]);
#pragma unroll
      for (int mi = 0; mi < 4; mi++)
#pragma unroll
        for (int ni = 0; ni < 4; ni++)
          acc[mi][ni] = mfma16(af[mi], bb[ni], acc[mi][ni]);
    }
  }

#pragma unroll
  for (int mi = 0; mi < 4; mi++)
#pragma unroll
    for (int ni = 0; ni < 4; ni++) {
      int rb = m0 + wm + mi*16 + g*4;
      int col = n0 + wn + ni*16 + c;
#pragma unroll
      for (int r = 0; r < 4; r++)
        Cm[(size_t)(rb + r)*Nd + col] = acc[mi][ni][r];   // C/D: row=4g+r, col=c
    }
}

// ---------------- causal GQA flash attention ----------------
// Q [B,H,T,D], K [B,HKV,T,D], Vt [B,HKV,D,T] (all bf16) -> Ao [B,T,H*D] bf16
#define QBLK 64
#define KVBLK 64
#define PPAD 72   // 16B-aligned row stride for P LDS

__global__ __launch_bounds__(256, 2)
void attn_fwd(const u16* __restrict__ Q, const u16* __restrict__ K,
              const u16* __restrict__ Vt, u16* __restrict__ Ao) {
  __shared__ u16 sK[KVBLK * D_];      // [64 kv][128 d]
  __shared__ u16 sV[D_ * KVBLK];      // [128 d][64 kv]
  __shared__ u16 sP[4][16 * PPAD];    // per-wave P tile
  const int tid = threadIdx.x;
  const int wave = tid >> 6, lane = tid & 63;
  const int g = lane >> 4, c = lane & 15;
  const int bid = blockIdx.x;
  const int qt = bid & 31;
  const int h  = (bid >> 5) & 15;
  const int b  = bid >> 9;
  const int hkv = h >> 1;             // GQA group of 2
  const int q0 = qt * QBLK;

  const u16* Qp = Q  + ((size_t)(b*H_ + h)*T_ + q0 + wave*16) * D_;
  const u16* Kp = K  + (size_t)(b*HKV_ + hkv) * T_ * D_;
  const u16* Vp = Vt + (size_t)(b*HKV_ + hkv) * D_ * T_;

  bf16x8 qf[4];
#pragma unroll
  for (int ks = 0; ks < 4; ks++)      // A-frag: row=c, k = ks*32 + 8g + j
    qf[ks] = *reinterpret_cast<const bf16x8*>(Qp + (size_t)c*D_ + ks*32 + g*8);

  f32x4 o[8] = {};
  float m_r[4], l_r[4];
#pragma unroll
  for (int r = 0; r < 4; r++) { m_r[r] = -1e30f; l_r[r] = 0.f; }

  const float scale = 0.08838834764831845f;  // 1/sqrt(128)
  const int ntiles = q0 / KVBLK + 1;

  for (int t = 0; t < ntiles; t++) {
    const int kv0 = t * KVBLK;
    __syncthreads();
#pragma unroll
    for (int i = 0; i < 4; i++) {
      int chunk = i*4 + wave;
      gload_lds16(Kp + (size_t)(kv0 + chunk*4 + (lane>>4))*D_ + (lane&15)*8,
                  &sK[chunk*512]);
      gload_lds16(Vp + (size_t)(chunk*8 + (lane>>3))*T_ + kv0 + (lane&7)*8,
                  &sV[chunk*512]);
    }
    __syncthreads();

    // S = Q K^T (per-wave 16 rows x 64 cols)
    f32x4 sf[4] = {};
#pragma unroll
    for (int ks = 0; ks < 4; ks++) {
#pragma unroll
      for (int nf = 0; nf < 4; nf++) {
        bf16x8 kb = *reinterpret_cast<const bf16x8*>(&sK[(nf*16 + c)*D_ + ks*32 + g*8]);
        sf[nf] = mfma16(qf[ks], kb, sf[nf]);
      }
    }

    float sv[4][4];
    const bool maskt = (t == ntiles - 1);
#pragma unroll
    for (int nf = 0; nf < 4; nf++)
#pragma unroll
      for (int r = 0; r < 4; r++) {
        float s = sf[nf][r] * scale;
        if (maskt) {
          int col = kv0 + nf*16 + c;
          int row = q0 + wave*16 + g*4 + r;
          if (col > row) s = -1e30f;
        }
        sv[nf][r] = s;
      }

    float alpha[4];
#pragma unroll
    for (int r = 0; r < 4; r++) {
      float mx = fmaxf(fmaxf(sv[0][r], sv[1][r]), fmaxf(sv[2][r], sv[3][r]));
#pragma unroll
      for (int off = 1; off < 16; off <<= 1)
        mx = fmaxf(mx, __shfl_xor(mx, off, 64));   // 16-lane row group
      float mn = fmaxf(m_r[r], mx);
      alpha[r] = __expf(m_r[r] - mn);
      m_r[r] = mn;
    }

    float psum[4] = {0.f, 0.f, 0.f, 0.f};
#pragma unroll
    for (int nf = 0; nf < 4; nf++)
#pragma unroll
      for (int r = 0; r < 4; r++) {
        float p = __expf(sv[nf][r] - m_r[r]);      // masked -> exp(-inf)=0
        psum[r] += p;
        sP[wave][(g*4 + r)*PPAD + nf*16 + c] = f2bf(p);  // D-layout store
      }

#pragma unroll
    for (int r = 0; r < 4; r++) {
      float s = psum[r];
#pragma unroll
      for (int off = 1; off < 16; off <<= 1)
        s += __shfl_xor(s, off, 64);
      l_r[r] = l_r[r]*alpha[r] + s;
    }

#pragma unroll
    for (int dt = 0; dt < 8; dt++)
#pragma unroll
      for (int r = 0; r < 4; r++) o[dt][r] *= alpha[r];

    // PV: read P back in A-layout, V from transposed tile (k-contiguous)
#pragma unroll
    for (int kk = 0; kk < 2; kk++) {
      bf16x8 pa = *reinterpret_cast<const bf16x8*>(&sP[wave][c*PPAD + kk*32 + g*8]);
#pragma unroll
      for (int dt = 0; dt < 8; dt++) {
        bf16x8 vb = *reinterpret_cast<const bf16x8*>(&sV[(dt*16 + c)*KVBLK + kk*32 + g*8]);
        o[dt] = mfma16(pa, vb, o[dt]);
      }
    }
  }

  float inv[4];
#pragma unroll
  for (int r = 0; r < 4; r++) inv[r] = 1.f / l_r[r];
  u16* Aop = Ao + ((size_t)(b*T_) + q0 + wave*16) * (H_*D_) + h*D_;
#pragma unroll
  for (int dt = 0; dt < 8; dt++)
#pragma unroll
    for (int r = 0; r < 4; r++)
      Aop[(size_t)(g*4 + r)*(H_*D_) + dt*16 + c] = f2bf(o[dt][r] * inv[r]);
}

// ---------------- launch ----------------
extern "C" void kernel_launch(void* const* d_in, const int* in_sizes, int n_in,
                              void* d_out, int out_size, void* d_ws, size_t ws_size,
                              hipStream_t stream) {
  const float* x  = (const float*)d_in[0];
  const float* Wq = (const float*)d_in[1];
  const float* Wk = (const float*)d_in[2];
  const float* Wv = (const float*)d_in[3];
  const float* Wp = (const float*)d_in[4];
  float* out = (float*)d_out;
  char* ws = (char*)d_ws;

  size_t off = 0;
  auto alloc = [&](size_t bytes) { size_t o = off; off += (bytes + 255) & ~(size_t)255; return o; };
  u16*  xb  = (u16*)(ws + alloc((size_t)M_*C_*2));
  u16*  wqT = (u16*)(ws + alloc((size_t)C_*C_*2));
  u16*  wkT = (u16*)(ws + alloc((size_t)NKV_*C_*2));
  u16*  wvT = (u16*)(ws + alloc((size_t)NKV_*C_*2));
  u16*  wpT = (u16*)(ws + alloc((size_t)C_*C_*2));
  float* qf = (float*)(ws + alloc((size_t)M_*C_*4));
  float* kf = (float*)(ws + alloc((size_t)M_*NKV_*4));
  float* vf = (float*)(ws + alloc((size_t)M_*NKV_*4));
  u16*  Qb  = (u16*)(ws + alloc((size_t)M_*C_*2));
  u16*  Kb  = (u16*)(ws + alloc((size_t)M_*NKV_*2));
  u16*  Vtb = (u16*)(ws + alloc((size_t)M_*NKV_*2));
  float* cs = (float*)(ws + alloc((size_t)T_*64*4));
  float* sn = (float*)(ws + alloc((size_t)T_*64*4));
  u16*  Ao  = (u16*)qf;   // alias: qf is dead after rope_apply(q)
  // total ws footprint ~144 MB

  cvt_bf16<<<(M_*C_/4 + 255)/256, 256, 0, stream>>>(x, xb, M_*C_/4);
  wtrans<<<(C_/64)*(C_/64),   256, 0, stream>>>(Wq, wqT, C_, C_);
  wtrans<<<(C_/64)*(NKV_/64), 256, 0, stream>>>(Wk, wkT, C_, NKV_);
  wtrans<<<(C_/64)*(NKV_/64), 256, 0, stream>>>(Wv, wvT, C_, NKV_);
  wtrans<<<(C_/64)*(C_/64),   256, 0, stream>>>(Wp, wpT, C_, C_);
  rope_tab<<<(T_*64 + 255)/256, 256, 0, stream>>>(cs, sn);

  gemm_bt<<<(M_/BM)*(C_/BN),   256, 0, stream>>>(xb, wqT, qf, M_, C_, C_);
  gemm_bt<<<(M_/BM)*(NKV_/BN), 256, 0, stream>>>(xb, wkT, kf, M_, NKV_, C_);
  gemm_bt<<<(M_/BM)*(NKV_/BN), 256, 0, stream>>>(xb, wvT, vf, M_, NKV_, C_);

  rope_apply<<<(B_*T_*H_*64)/256,   256, 0, stream>>>(qf, Qb, cs, sn, H_);
  rope_apply<<<(B_*T_*HKV_*64)/256, 256, 0, stream>>>(kf, Kb, cs, sn, HKV_);
  vtrans<<<B_*HKV_*(T_/64)*(D_/64), 256, 0, stream>>>(vf, Vtb);

  attn_fwd<<<B_*H_*(T_/QBLK), 256, 0, stream>>>(Qb, Kb, Vtb, Ao);

  gemm_bt<<<(M_/BM)*(C_/BN), 256, 0, stream>>>(Ao, wpT, out, M_, C_, C_);
}

// Round 3
// 510.779 us; speedup vs baseline: 1.2477x; 1.2477x over previous
//
#include <hip/hip_runtime.h>
#include <cstdint>
#include <cstddef>

#define B_ 2
#define T_ 2048
#define C_ 2048
#define H_ 16
#define HKV_ 8
#define D_ 128
#define M_ (B_*T_)          // 4096 tokens
#define NKV_ (HKV_*D_)      // 1024

typedef unsigned short u16;
typedef __bf16 bf16_t;
typedef bf16_t bf16x8 __attribute__((ext_vector_type(8)));
typedef float f32x4 __attribute__((ext_vector_type(4)));

__device__ __forceinline__ u16 f2bf(float f) {
  union { float fl; uint32_t u; } v; v.fl = f;
  uint32_t u = v.u;
  return (u16)((u + 0x7fffu + ((u >> 16) & 1u)) >> 16);  // RNE
}

__device__ __forceinline__ void gload_lds16(const void* g, void* l) {
  // async global->LDS, 16B/lane; LDS dest = wave-uniform base + lane*16
  __builtin_amdgcn_global_load_lds(
      (const __attribute__((address_space(1))) unsigned int*)g,
      (__attribute__((address_space(3))) unsigned int*)l, 16, 0, 0);
}

__device__ __forceinline__ f32x4 mfma16(bf16x8 a, bf16x8 b, f32x4 c) {
  return __builtin_amdgcn_mfma_f32_16x16x32_bf16(a, b, c, 0, 0, 0);
}

// ---------------- elementwise f32 -> bf16 ----------------
__global__ void cvt_bf16(const float* __restrict__ in, u16* __restrict__ out, int n4) {
  int i = blockIdx.x * blockDim.x + threadIdx.x;
  if (i >= n4) return;
  float4 f = reinterpret_cast<const float4*>(in)[i];
  ushort4 o;
  o.x = f2bf(f.x); o.y = f2bf(f.y); o.z = f2bf(f.z); o.w = f2bf(f.w);
  reinterpret_cast<ushort4*>(out)[i] = o;
}

// ------- tiled transpose+convert: W[K][N] f32 -> WT[N][K] bf16 -------
__global__ void wtrans(const float* __restrict__ w, u16* __restrict__ wt, int Kd, int Nd) {
  __shared__ float tile[64][65];
  int ntt = Nd >> 6;
  int nt = blockIdx.x % ntt, kt = blockIdx.x / ntt;
  int cc = threadIdx.x & 63, r0 = threadIdx.x >> 6;
#pragma unroll
  for (int i = 0; i < 16; i++) {
    int r = r0 + i*4;
    tile[r][cc] = w[(size_t)(kt*64 + r)*Nd + nt*64 + cc];
  }
  __syncthreads();
#pragma unroll
  for (int i = 0; i < 16; i++) {
    int r = r0 + i*4;
    wt[(size_t)(nt*64 + r)*Kd + kt*64 + cc] = f2bf(tile[cc][r]);
  }
}

// ---------------- RoPE cos/sin table [T][64] f32 ----------------
__global__ void rope_tab(float* __restrict__ cs, float* __restrict__ sn) {
  int idx = blockIdx.x * blockDim.x + threadIdx.x;
  if (idx >= T_*64) return;
  int i = idx & 63, t = idx >> 6;
  float inv = powf(10000.f, -(float)i / 64.f);
  float fr = (float)t * inv;
  cs[idx] = cosf(fr);
  sn[idx] = sinf(fr);
}

// ---- rope + reshape: src f32 [B*T, nh*D] -> dst bf16 [B, nh, T, D] ----
__global__ void rope_apply(const float* __restrict__ src, u16* __restrict__ dst,
                           const float* __restrict__ cs, const float* __restrict__ sn,
                           int nheads) {
  int idx = blockIdx.x * blockDim.x + threadIdx.x;
  if (idx >= B_*T_*nheads*64) return;
  int i = idx & 63;
  int hh = (idx >> 6) % nheads;
  int bt = (idx >> 6) / nheads;
  int t = bt % T_, b = bt / T_;
  size_t sbase = (size_t)bt * nheads * D_ + (size_t)hh * D_;
  size_t obase = ((size_t)(b*nheads + hh) * T_ + t) * D_;
  float x1 = src[sbase + i], x2 = src[sbase + 64 + i];
  float cv = cs[t*64 + i], sv = sn[t*64 + i];
  dst[obase + i]      = f2bf(x1*cv - x2*sv);
  dst[obase + 64 + i] = f2bf(x2*cv + x1*sv);
}

// -- V: f32 [B*T, HKV*D] -> bf16 Vt [B, HKV, D, T] (transposed per head) --
__global__ void vtrans(const float* __restrict__ v, u16* __restrict__ vt) {
  __shared__ float tile[64][65];
  int bid = blockIdx.x;
  int dt = bid & 1;
  int tt = (bid >> 1) & 31;
  int h  = (bid >> 6) & 7;
  int b  = bid >> 9;
  int cc = threadIdx.x & 63, r0 = threadIdx.x >> 6;
#pragma unroll
  for (int i = 0; i < 16; i++) {
    int r = r0 + i*4;
    tile[r][cc] = v[(size_t)(b*T_ + tt*64 + r)*NKV_ + h*D_ + dt*64 + cc];
  }
  __syncthreads();
#pragma unroll
  for (int i = 0; i < 16; i++) {
    int r = r0 + i*4;  // d index within tile
    vt[((size_t)(b*HKV_ + h)*D_ + dt*64 + r)*T_ + tt*64 + cc] = f2bf(tile[cc][r]);
  }
}

// ---------------- GEMM: C[M][N] f32 = A[M][K] bf16 * Bt[N][K] bf16 ----------------
#define BM 128
#define BN 128
#define BK 64

__global__ __launch_bounds__(256, 2)
void gemm_bt(const u16* __restrict__ A, const u16* __restrict__ Bt,
             float* __restrict__ Cm, int Md, int Nd, int Kd) {
  __shared__ u16 sA[BM * BK];   // [128][64]
  __shared__ u16 sB[BN * BK];   // [128][64]
  const int tid = threadIdx.x;
  const int wave = tid >> 6, lane = tid & 63;
  const int g = lane >> 4, c = lane & 15;
  const int nbn = Nd / BN;
  const int bm = blockIdx.x / nbn, bn = blockIdx.x % nbn;
  const int m0 = bm * BM, n0 = bn * BN;
  const int wm = (wave >> 1) * 64, wn = (wave & 1) * 64;
  const int srow = lane >> 3, skcol = (lane & 7) * 8;

  f32x4 acc[4][4] = {};

  for (int k0 = 0; k0 < Kd; k0 += BK) {
    __syncthreads();
#pragma unroll
    for (int i = 0; i < 4; i++) {
      int chunk = i*4 + wave;              // wave-uniform
      int row = chunk*8 + srow;
      gload_lds16(A  + (size_t)(m0 + row)*Kd + k0 + skcol, &sA[chunk*512]);
      gload_lds16(Bt + (size_t)(n0 + row)*Kd + k0 + skcol, &sB[chunk*512]);
    }
    __syncthreads();
#pragma unroll
    for (int ks = 0; ks < 2; ks++) {
      bf16x8 af[4], bb[4];
#pragma unroll
      for (int mi = 0; mi < 4; mi++)
        af[mi] = *reinterpret_cast<const bf16x8*>(&sA[(wm + mi*16 + c)*BK + ks*32 + g*8]);
#pragma unroll
      for (int ni = 0; ni < 4; ni++)
        bb[ni] = *reinterpret_cast<const bf16x8*>(&sB[(wn + ni*16 + c)*BK + ks*32 + g*8]);
#pragma unroll
      for (int mi = 0; mi < 4; mi++)
#pragma unroll
        for (int ni = 0; ni < 4; ni++)
          acc[mi][ni] = mfma16(af[mi], bb[ni], acc[mi][ni]);
    }
  }

#pragma unroll
  for (int mi = 0; mi < 4; mi++)
#pragma unroll
    for (int ni = 0; ni < 4; ni++) {
      int rb = m0 + wm + mi*16 + g*4;
      int col = n0 + wn + ni*16 + c;
#pragma unroll
      for (int r = 0; r < 4; r++)
        Cm[(size_t)(rb + r)*Nd + col] = acc[mi][ni][r];   // C/D: row=4g+r, col=c
    }
}

// ---------------- causal GQA flash attention (v2) ----------------
// Q [B,H,T,D], K [B,HKV,T,D], Vt [B,HKV,D,T] (all bf16) -> Ao [B,T,H*D] bf16
// v2: XOR-swizzled sK/sV (T2, via pre-swizzled global src + swizzled read),
//     double-buffered K/V (T3-min 2-phase), reversed-qt dispatch (balance),
//     s_setprio around MFMA clusters (T5).
#define QBLK 64
#define KVBLK 64
#define PPAD 72   // 16B-aligned row stride for P LDS

__global__ __launch_bounds__(256, 2)
void attn_fwd(const u16* __restrict__ Q, const u16* __restrict__ K,
              const u16* __restrict__ Vt, u16* __restrict__ Ao) {
  __shared__ u16 sK[2][KVBLK * D_];   // [64 kv][128 d], slot^=(row&7) swizzle
  __shared__ u16 sV[2][D_ * KVBLK];   // [128 d][64 kv], slot^=(row&7) swizzle
  __shared__ u16 sP[4][16 * PPAD];    // per-wave P tile (2-way max, free)
  const int tid = threadIdx.x;
  const int wave = tid >> 6, lane = tid & 63;
  const int g = lane >> 4, c = lane & 15;
  const int bid = blockIdx.x;
  const int qt = (T_/QBLK - 1) - (bid & 31);   // reversed: big blocks first
  const int h  = (bid >> 5) & 15;
  const int b  = bid >> 9;
  const int hkv = h >> 1;             // GQA group of 2
  const int q0 = qt * QBLK;

  const u16* Qp = Q  + ((size_t)(b*H_ + h)*T_ + q0 + wave*16) * D_;
  const u16* Kp = K  + (size_t)(b*HKV_ + hkv) * T_ * D_;
  const u16* Vp = Vt + (size_t)(b*HKV_ + hkv) * D_ * T_;

  bf16x8 qf[4];
#pragma unroll
  for (int ks = 0; ks < 4; ks++)      // A-frag: row=c, k = ks*32 + 8g + j
    qf[ks] = *reinterpret_cast<const bf16x8*>(Qp + (size_t)c*D_ + ks*32 + g*8);

  f32x4 o[8] = {};
  float m_r[4], l_r[4];
#pragma unroll
  for (int r = 0; r < 4; r++) { m_r[r] = -1e30f; l_r[r] = 0.f; }

  const float scale = 0.08838834764831845f;  // 1/sqrt(128)
  const int ntiles = qt + 1;

  // staging geometry (per lane)
  const int krow = (lane >> 4);                 // + chunk*4
  const int vrow = (lane >> 3);                 // + chunk*8
  // inverse-swizzled global column slots (16B units)
  // K: row r has 16 slots; phys slot s holds logical s^(r&7)
  // V: row d has 8 slots;  phys slot s holds logical s^(d&7)

  // stage tile t into buffer bsel
  auto stage = [&](int t, int bsel) {
    const int kv0 = t * KVBLK;
#pragma unroll
    for (int i = 0; i < 4; i++) {
      int chunk = i*4 + wave;                   // wave-uniform
      int kr = chunk*4 + krow;                  // 0..63
      int kslot = (lane & 15) ^ (kr & 7);
      gload_lds16(Kp + (size_t)(kv0 + kr)*D_ + kslot*8, &sK[bsel][chunk*512]);
      int vr = chunk*8 + vrow;                  // 0..127
      int vslot = (lane & 7) ^ (vr & 7);
      gload_lds16(Vp + (size_t)vr*T_ + kv0 + vslot*8, &sV[bsel][chunk*512]);
    }
  };

  stage(0, 0);
  __syncthreads();                              // drains vmcnt

  int cur = 0;
  for (int t = 0; t < ntiles; t++) {
    const int kv0 = t * KVBLK;
    if (t + 1 < ntiles) stage(t + 1, cur ^ 1);  // prefetch, stays in flight

    // S = Q K^T (per-wave 16 rows x 64 cols); swizzled K read
    f32x4 sf[4] = {};
    __builtin_amdgcn_s_setprio(1);
#pragma unroll
    for (int ks = 0; ks < 4; ks++) {
#pragma unroll
      for (int nf = 0; nf < 4; nf++) {
        int slot = (ks*4 + g) ^ (c & 7);
        bf16x8 kb = *reinterpret_cast<const bf16x8*>(&sK[cur][(nf*16 + c)*D_ + slot*8]);
        sf[nf] = mfma16(qf[ks], kb, sf[nf]);
      }
    }
    __builtin_amdgcn_s_setprio(0);

    float sv[4][4];
    const bool maskt = (t == ntiles - 1);
#pragma unroll
    for (int nf = 0; nf < 4; nf++)
#pragma unroll
      for (int r = 0; r < 4; r++) {
        float s = sf[nf][r] * scale;
        if (maskt) {
          int col = kv0 + nf*16 + c;
          int row = q0 + wave*16 + g*4 + r;
          if (col > row) s = -1e30f;
        }
        sv[nf][r] = s;
      }

    float alpha[4];
#pragma unroll
    for (int r = 0; r < 4; r++) {
      float mx = fmaxf(fmaxf(sv[0][r], sv[1][r]), fmaxf(sv[2][r], sv[3][r]));
#pragma unroll
      for (int off = 1; off < 16; off <<= 1)
        mx = fmaxf(mx, __shfl_xor(mx, off, 64));   // 16-lane row group
      float mn = fmaxf(m_r[r], mx);
      alpha[r] = __expf(m_r[r] - mn);
      m_r[r] = mn;
    }

    float psum[4] = {0.f, 0.f, 0.f, 0.f};
#pragma unroll
    for (int nf = 0; nf < 4; nf++)
#pragma unroll
      for (int r = 0; r < 4; r++) {
        float p = __expf(sv[nf][r] - m_r[r]);      // masked -> exp(-inf)=0
        psum[r] += p;
        sP[wave][(g*4 + r)*PPAD + nf*16 + c] = f2bf(p);  // D-layout store
      }

#pragma unroll
    for (int r = 0; r < 4; r++) {
      float s = psum[r];
#pragma unroll
      for (int off = 1; off < 16; off <<= 1)
        s += __shfl_xor(s, off, 64);
      l_r[r] = l_r[r]*alpha[r] + s;
    }

#pragma unroll
    for (int dt = 0; dt < 8; dt++)
#pragma unroll
      for (int r = 0; r < 4; r++) o[dt][r] *= alpha[r];

    // PV: read P back in A-layout, swizzled V read (k-contiguous)
    __builtin_amdgcn_s_setprio(1);
#pragma unroll
    for (int kk = 0; kk < 2; kk++) {
      bf16x8 pa = *reinterpret_cast<const bf16x8*>(&sP[wave][c*PPAD + kk*32 + g*8]);
#pragma unroll
      for (int dt = 0; dt < 8; dt++) {
        int slot = (kk*4 + g) ^ (c & 7);
        bf16x8 vb = *reinterpret_cast<const bf16x8*>(&sV[cur][(dt*16 + c)*KVBLK + slot*8]);
        o[dt] = mfma16(pa, vb, o[dt]);
      }
    }
    __builtin_amdgcn_s_setprio(0);

    __syncthreads();   // one barrier/tile: drains prefetch writes + joins readers
    cur ^= 1;
  }

  float inv[4];
#pragma unroll
  for (int r = 0; r < 4; r++) inv[r] = 1.f / l_r[r];
  u16* Aop = Ao + ((size_t)(b*T_) + q0 + wave*16) * (H_*D_) + h*D_;
#pragma unroll
  for (int dt = 0; dt < 8; dt++)
#pragma unroll
    for (int r = 0; r < 4; r++)
      Aop[(size_t)(g*4 + r)*(H_*D_) + dt*16 + c] = f2bf(o[dt][r] * inv[r]);
}

// ---------------- launch ----------------
extern "C" void kernel_launch(void* const* d_in, const int* in_sizes, int n_in,
                              void* d_out, int out_size, void* d_ws, size_t ws_size,
                              hipStream_t stream) {
  const float* x  = (const float*)d_in[0];
  const float* Wq = (const float*)d_in[1];
  const float* Wk = (const float*)d_in[2];
  const float* Wv = (const float*)d_in[3];
  const float* Wp = (const float*)d_in[4];
  float* out = (float*)d_out;
  char* ws = (char*)d_ws;

  size_t off = 0;
  auto alloc = [&](size_t bytes) { size_t o = off; off += (bytes + 255) & ~(size_t)255; return o; };
  u16*  xb  = (u16*)(ws + alloc((size_t)M_*C_*2));
  u16*  wqT = (u16*)(ws + alloc((size_t)C_*C_*2));
  u16*  wkT = (u16*)(ws + alloc((size_t)NKV_*C_*2));
  u16*  wvT = (u16*)(ws + alloc((size_t)NKV_*C_*2));
  u16*  wpT = (u16*)(ws + alloc((size_t)C_*C_*2));
  float* qf = (float*)(ws + alloc((size_t)M_*C_*4));
  float* kf = (float*)(ws + alloc((size_t)M_*NKV_*4));
  float* vf = (float*)(ws + alloc((size_t)M_*NKV_*4));
  u16*  Qb  = (u16*)(ws + alloc((size_t)M_*C_*2));
  u16*  Kb  = (u16*)(ws + alloc((size_t)M_*NKV_*2));
  u16*  Vtb = (u16*)(ws + alloc((size_t)M_*NKV_*2));
  float* cs = (float*)(ws + alloc((size_t)T_*64*4));
  float* sn = (float*)(ws + alloc((size_t)T_*64*4));
  u16*  Ao  = (u16*)qf;   // alias: qf is dead after rope_apply(q)
  // total ws footprint ~144 MB

  cvt_bf16<<<(M_*C_/4 + 255)/256, 256, 0, stream>>>(x, xb, M_*C_/4);
  wtrans<<<(C_/64)*(C_/64),   256, 0, stream>>>(Wq, wqT, C_, C_);
  wtrans<<<(C_/64)*(NKV_/64), 256, 0, stream>>>(Wk, wkT, C_, NKV_);
  wtrans<<<(C_/64)*(NKV_/64), 256, 0, stream>>>(Wv, wvT, C_, NKV_);
  wtrans<<<(C_/64)*(C_/64),   256, 0, stream>>>(Wp, wpT, C_, C_);
  rope_tab<<<(T_*64 + 255)/256, 256, 0, stream>>>(cs, sn);

  gemm_bt<<<(M_/BM)*(C_/BN),   256, 0, stream>>>(xb, wqT, qf, M_, C_, C_);
  gemm_bt<<<(M_/BM)*(NKV_/BN), 256, 0, stream>>>(xb, wkT, kf, M_, NKV_, C_);
  gemm_bt<<<(M_/BM)*(NKV_/BN), 256, 0, stream>>>(xb, wvT, vf, M_, NKV_, C_);

  rope_apply<<<(B_*T_*H_*64)/256,   256, 0, stream>>>(qf, Qb, cs, sn, H_);
  rope_apply<<<(B_*T_*HKV_*64)/256, 256, 0, stream>>>(kf, Kb, cs, sn, HKV_);
  vtrans<<<B_*HKV_*(T_/64)*(D_/64), 256, 0, stream>>>(vf, Vtb);

  attn_fwd<<<B_*H_*(T_/QBLK), 256, 0, stream>>>(Qb, Kb, Vtb, Ao);

  gemm_bt<<<(M_/BM)*(C_/BN), 256, 0, stream>>>(Ao, wpT, out, M_, C_, C_);
}

// Round 4
// 469.984 us; speedup vs baseline: 1.3560x; 1.0868x over previous
//
#include <hip/hip_runtime.h>
#include <cstdint>
#include <cstddef>

#define B_ 2
#define T_ 2048
#define C_ 2048
#define H_ 16
#define HKV_ 8
#define D_ 128
#define M_ (B_*T_)          // 4096 tokens
#define NKV_ (HKV_*D_)      // 1024

typedef unsigned short u16;
typedef __bf16 bf16_t;
typedef bf16_t bf16x8 __attribute__((ext_vector_type(8)));
typedef float f32x4 __attribute__((ext_vector_type(4)));

__device__ __forceinline__ u16 f2bf(float f) {
  union { float fl; uint32_t u; } v; v.fl = f;
  uint32_t u = v.u;
  return (u16)((u + 0x7fffu + ((u >> 16) & 1u)) >> 16);  // RNE
}

__device__ __forceinline__ void gload_lds16(const void* g, void* l) {
  // async global->LDS, 16B/lane; LDS dest = wave-uniform base + lane*16
  __builtin_amdgcn_global_load_lds(
      (const __attribute__((address_space(1))) unsigned int*)g,
      (__attribute__((address_space(3))) unsigned int*)l, 16, 0, 0);
}

__device__ __forceinline__ f32x4 mfma16(bf16x8 a, bf16x8 b, f32x4 c) {
  return __builtin_amdgcn_mfma_f32_16x16x32_bf16(a, b, c, 0, 0, 0);
}

// 2x f32 -> packed bf16 pair (lo = a, hi = b). T12 recipe: no builtin on gfx950.
__device__ __forceinline__ uint32_t cvt_pk_bf16(float a, float b) {
  uint32_t r;
  asm("v_cvt_pk_bf16_f32 %0, %1, %2" : "=v"(r) : "v"(a), "v"(b));
  return r;
}

// ---------------- elementwise f32 -> bf16 ----------------
__global__ void cvt_bf16(const float* __restrict__ in, u16* __restrict__ out, int n4) {
  int i = blockIdx.x * blockDim.x + threadIdx.x;
  if (i >= n4) return;
  float4 f = reinterpret_cast<const float4*>(in)[i];
  ushort4 o;
  o.x = f2bf(f.x); o.y = f2bf(f.y); o.z = f2bf(f.z); o.w = f2bf(f.w);
  reinterpret_cast<ushort4*>(out)[i] = o;
}

// ------- tiled transpose+convert: W[K][N] f32 -> WT[N][K] bf16 -------
__global__ void wtrans(const float* __restrict__ w, u16* __restrict__ wt, int Kd, int Nd) {
  __shared__ float tile[64][65];
  int ntt = Nd >> 6;
  int nt = blockIdx.x % ntt, kt = blockIdx.x / ntt;
  int cc = threadIdx.x & 63, r0 = threadIdx.x >> 6;
#pragma unroll
  for (int i = 0; i < 16; i++) {
    int r = r0 + i*4;
    tile[r][cc] = w[(size_t)(kt*64 + r)*Nd + nt*64 + cc];
  }
  __syncthreads();
#pragma unroll
  for (int i = 0; i < 16; i++) {
    int r = r0 + i*4;
    wt[(size_t)(nt*64 + r)*Kd + kt*64 + cc] = f2bf(tile[cc][r]);
  }
}

// ---------------- RoPE cos/sin table [T][64] f32 ----------------
__global__ void rope_tab(float* __restrict__ cs, float* __restrict__ sn) {
  int idx = blockIdx.x * blockDim.x + threadIdx.x;
  if (idx >= T_*64) return;
  int i = idx & 63, t = idx >> 6;
  float inv = powf(10000.f, -(float)i / 64.f);
  float fr = (float)t * inv;
  cs[idx] = cosf(fr);
  sn[idx] = sinf(fr);
}

// ---- rope + reshape: src f32 [B*T, nh*D] -> dst bf16 [B, nh, T, D] ----
__global__ void rope_apply(const float* __restrict__ src, u16* __restrict__ dst,
                           const float* __restrict__ cs, const float* __restrict__ sn,
                           int nheads) {
  int idx = blockIdx.x * blockDim.x + threadIdx.x;
  if (idx >= B_*T_*nheads*64) return;
  int i = idx & 63;
  int hh = (idx >> 6) % nheads;
  int bt = (idx >> 6) / nheads;
  int t = bt % T_, b = bt / T_;
  size_t sbase = (size_t)bt * nheads * D_ + (size_t)hh * D_;
  size_t obase = ((size_t)(b*nheads + hh) * T_ + t) * D_;
  float x1 = src[sbase + i], x2 = src[sbase + 64 + i];
  float cv = cs[t*64 + i], sv = sn[t*64 + i];
  dst[obase + i]      = f2bf(x1*cv - x2*sv);
  dst[obase + 64 + i] = f2bf(x2*cv + x1*sv);
}

// -- V: f32 [B*T, HKV*D] -> bf16 Vt [B, HKV, D, T] (transposed per head) --
__global__ void vtrans(const float* __restrict__ v, u16* __restrict__ vt) {
  __shared__ float tile[64][65];
  int bid = blockIdx.x;
  int dt = bid & 1;
  int tt = (bid >> 1) & 31;
  int h  = (bid >> 6) & 7;
  int b  = bid >> 9;
  int cc = threadIdx.x & 63, r0 = threadIdx.x >> 6;
#pragma unroll
  for (int i = 0; i < 16; i++) {
    int r = r0 + i*4;
    tile[r][cc] = v[(size_t)(b*T_ + tt*64 + r)*NKV_ + h*D_ + dt*64 + cc];
  }
  __syncthreads();
#pragma unroll
  for (int i = 0; i < 16; i++) {
    int r = r0 + i*4;  // d index within tile
    vt[((size_t)(b*HKV_ + h)*D_ + dt*64 + r)*T_ + tt*64 + cc] = f2bf(tile[cc][r]);
  }
}

// ---------------- GEMM: C[M][N] f32 = A[M][K] bf16 * Bt[N][K] bf16 ----------------
#define BM 128
#define BN 128
#define BK 64

__global__ __launch_bounds__(256, 2)
void gemm_bt(const u16* __restrict__ A, const u16* __restrict__ Bt,
             float* __restrict__ Cm, int Md, int Nd, int Kd) {
  __shared__ u16 sA[BM * BK];   // [128][64]
  __shared__ u16 sB[BN * BK];   // [128][64]
  const int tid = threadIdx.x;
  const int wave = tid >> 6, lane = tid & 63;
  const int g = lane >> 4, c = lane & 15;
  const int nbn = Nd / BN;
  const int bm = blockIdx.x / nbn, bn = blockIdx.x % nbn;
  const int m0 = bm * BM, n0 = bn * BN;
  const int wm = (wave >> 1) * 64, wn = (wave & 1) * 64;
  const int srow = lane >> 3, skcol = (lane & 7) * 8;

  f32x4 acc[4][4] = {};

  for (int k0 = 0; k0 < Kd; k0 += BK) {
    __syncthreads();
#pragma unroll
    for (int i = 0; i < 4; i++) {
      int chunk = i*4 + wave;              // wave-uniform
      int row = chunk*8 + srow;
      gload_lds16(A  + (size_t)(m0 + row)*Kd + k0 + skcol, &sA[chunk*512]);
      gload_lds16(Bt + (size_t)(n0 + row)*Kd + k0 + skcol, &sB[chunk*512]);
    }
    __syncthreads();
#pragma unroll
    for (int ks = 0; ks < 2; ks++) {
      bf16x8 af[4], bb[4];
#pragma unroll
      for (int mi = 0; mi < 4; mi++)
        af[mi] = *reinterpret_cast<const bf16x8*>(&sA[(wm + mi*16 + c)*BK + ks*32 + g*8]);
#pragma unroll
      for (int ni = 0; ni < 4; ni++)
        bb[ni] = *reinterpret_cast<const bf16x8*>(&sB[(wn + ni*16 + c)*BK + ks*32 + g*8]);
#pragma unroll
      for (int mi = 0; mi < 4; mi++)
#pragma unroll
        for (int ni = 0; ni < 4; ni++)
          acc[mi][ni] = mfma16(af[mi], bb[ni], acc[mi][ni]);
    }
  }

#pragma unroll
  for (int mi = 0; mi < 4; mi++)
#pragma unroll
    for (int ni = 0; ni < 4; ni++) {
      int rb = m0 + wm + mi*16 + g*4;
      int col = n0 + wn + ni*16 + c;
#pragma unroll
      for (int r = 0; r < 4; r++)
        Cm[(size_t)(rb + r)*Nd + col] = acc[mi][ni][r];   // C/D: row=4g+r, col=c
    }
}

// ---------------- causal GQA flash attention (v3) ----------------
// Q [B,H,T,D], K [B,HKV,T,D], Vt [B,HKV,D,T] (all bf16) -> Ao [B,T,H*D] bf16
// v3: swapped QK^T (mfma(K,Q)) -> in-register P, no sP LDS round-trip (T12),
//     per-lane scalar m/l, deferred l-reduce, defer-max (T13, THR=8),
//     cvt_pk_bf16 + shfl redistribution for PV A-frag.
// Layout facts (HW-verified by v2 passing): A/B frag lane holds row/col = c,
// k = ks*32 + g*8 + j; C/D: row = g*4+r, col = c.
#define QBLK 64
#define KVBLK 64

__global__ __launch_bounds__(256, 2)
void attn_fwd(const u16* __restrict__ Q, const u16* __restrict__ K,
              const u16* __restrict__ Vt, u16* __restrict__ Ao) {
  __shared__ u16 sK[2][KVBLK * D_];   // [64 kv][128 d], slot^=(row&7) swizzle
  __shared__ u16 sV[2][D_ * KVBLK];   // [128 d][64 kv], slot^=(row&7) swizzle
  const int tid = threadIdx.x;
  const int wave = tid >> 6, lane = tid & 63;
  const int g = lane >> 4, c = lane & 15;
  const int bid = blockIdx.x;
  const int qt = (T_/QBLK - 1) - (bid & 31);   // reversed: big blocks first
  const int h  = (bid >> 5) & 15;
  const int b  = bid >> 9;
  const int hkv = h >> 1;             // GQA group of 2
  const int q0 = qt * QBLK;

  const u16* Qp = Q  + ((size_t)(b*H_ + h)*T_ + q0 + wave*16) * D_;
  const u16* Kp = K  + (size_t)(b*HKV_ + hkv) * T_ * D_;
  const u16* Vp = Vt + (size_t)(b*HKV_ + hkv) * D_ * T_;

  bf16x8 qf[4];
#pragma unroll
  for (int ks = 0; ks < 4; ks++)      // frag: row=c, k = ks*32 + 8g + j
    qf[ks] = *reinterpret_cast<const bf16x8*>(Qp + (size_t)c*D_ + ks*32 + g*8);

  f32x4 o[8] = {};
  float m_r = -1e30f, l_r = 0.f;      // per-lane: q = q0 + wave*16 + c

  const float scale = 0.08838834764831845f;  // 1/sqrt(128)
  const int ntiles = qt + 1;
  const int qglob = q0 + wave*16 + c;

  // staging geometry (per lane)
  const int krow = (lane >> 4);                 // + chunk*4
  const int vrow = (lane >> 3);                 // + chunk*8

  auto stage = [&](int t, int bsel) {
    const int kv0 = t * KVBLK;
#pragma unroll
    for (int i = 0; i < 4; i++) {
      int chunk = i*4 + wave;                   // wave-uniform
      int kr = chunk*4 + krow;                  // 0..63
      int kslot = (lane & 15) ^ (kr & 7);
      gload_lds16(Kp + (size_t)(kv0 + kr)*D_ + kslot*8, &sK[bsel][chunk*512]);
      int vr = chunk*8 + vrow;                  // 0..127
      int vslot = (lane & 7) ^ (vr & 7);
      gload_lds16(Vp + (size_t)vr*T_ + kv0 + vslot*8, &sV[bsel][chunk*512]);
    }
  };

  stage(0, 0);
  __syncthreads();                              // drains vmcnt

  int cur = 0;
  for (int t = 0; t < ntiles; t++) {
    const int kv0 = t * KVBLK;
    if (t + 1 < ntiles) stage(t + 1, cur ^ 1);  // prefetch, stays in flight

    // Swapped QK^T: st[nf] = S[kv = kv0+nf*16+g*4+r][q = qglob]
    f32x4 st[4] = {};
    __builtin_amdgcn_s_setprio(1);
#pragma unroll
    for (int ks = 0; ks < 4; ks++) {
#pragma unroll
      for (int nf = 0; nf < 4; nf++) {
        int slot = (ks*4 + g) ^ (c & 7);
        bf16x8 kb = *reinterpret_cast<const bf16x8*>(&sK[cur][(nf*16 + c)*D_ + slot*8]);
        st[nf] = mfma16(kb, qf[ks], st[nf]);    // A=K (M=kv), B=Q (N=q)
      }
    }
    __builtin_amdgcn_s_setprio(0);

    // scale + causal mask (kv > q)
    float p[4][4];
    const bool maskt = (t == ntiles - 1);
#pragma unroll
    for (int nf = 0; nf < 4; nf++)
#pragma unroll
      for (int r = 0; r < 4; r++) {
        float s = st[nf][r] * scale;
        if (maskt && (kv0 + nf*16 + g*4 + r > qglob)) s = -1e30f;
        p[nf][r] = s;
      }

    // row max: per-lane tree over 16, then cross-g (lanes +-16, +-32)
    float mx0 = fmaxf(fmaxf(p[0][0], p[0][1]), fmaxf(p[0][2], p[0][3]));
    float mx1 = fmaxf(fmaxf(p[1][0], p[1][1]), fmaxf(p[1][2], p[1][3]));
    float mx2 = fmaxf(fmaxf(p[2][0], p[2][1]), fmaxf(p[2][2], p[2][3]));
    float mx3 = fmaxf(fmaxf(p[3][0], p[3][1]), fmaxf(p[3][2], p[3][3]));
    float mx = fmaxf(fmaxf(mx0, mx1), fmaxf(mx2, mx3));
    mx = fmaxf(mx, __shfl_xor(mx, 16, 64));
    mx = fmaxf(mx, __shfl_xor(mx, 32, 64));

    // defer-max (T13): only rescale when max grew past THR=8
    if (!__all(mx <= m_r + 8.f)) {
      float mn = fmaxf(m_r, mx);
      float alpha = __expf(m_r - mn);
      m_r = mn;
      l_r *= alpha;
      float aq[4];
#pragma unroll
      for (int r = 0; r < 4; r++) aq[r] = __shfl(alpha, g*4 + r, 64);
#pragma unroll
      for (int dt = 0; dt < 8; dt++)
#pragma unroll
        for (int r = 0; r < 4; r++) o[dt][r] *= aq[r];
    }

    // exp + per-lane partial sum (pairwise)
#pragma unroll
    for (int nf = 0; nf < 4; nf++)
#pragma unroll
      for (int r = 0; r < 4; r++) p[nf][r] = __expf(p[nf][r] - m_r);
    float s0 = (p[0][0] + p[0][1]) + (p[0][2] + p[0][3]);
    float s1 = (p[1][0] + p[1][1]) + (p[1][2] + p[1][3]);
    float s2 = (p[2][0] + p[2][1]) + (p[2][2] + p[2][3]);
    float s3 = (p[3][0] + p[3][1]) + (p[3][2] + p[3][3]);
    l_r += (s0 + s1) + (s2 + s3);

    // pack: pk[nf][w] = bf16 pair for kv = nf*16 + g*4 + 2w (lo), +1 (hi)
    uint32_t pk[4][2];
#pragma unroll
    for (int nf = 0; nf < 4; nf++) {
      pk[nf][0] = cvt_pk_bf16(p[nf][0], p[nf][1]);
      pk[nf][1] = cvt_pk_bf16(p[nf][2], p[nf][3]);
    }

    // redistribute to PV A-frag: pa[kk] elem j = P[q=c][kv = kk*32 + g*8 + j]
    // word t (t=0..3) = pk[kk*2 + (g>>1)][t&1] from lane ((2g + (t>>1))&3)*16 + c
    const int srcA = (((2*g)     & 3) << 4) | c;
    const int srcB = (((2*g + 1) & 3) << 4) | c;
    const bool hi = (g >> 1);
    bf16x8 pa[2];
#pragma unroll
    for (int kk = 0; kk < 2; kk++) {
      uint32_t a0 = (uint32_t)__shfl((int)pk[kk*2    ][0], srcA, 64);
      uint32_t a1 = (uint32_t)__shfl((int)pk[kk*2    ][1], srcA, 64);
      uint32_t b0 = (uint32_t)__shfl((int)pk[kk*2 + 1][0], srcA, 64);
      uint32_t b1 = (uint32_t)__shfl((int)pk[kk*2 + 1][1], srcA, 64);
      uint32_t a2 = (uint32_t)__shfl((int)pk[kk*2    ][0], srcB, 64);
      uint32_t a3 = (uint32_t)__shfl((int)pk[kk*2    ][1], srcB, 64);
      uint32_t b2 = (uint32_t)__shfl((int)pk[kk*2 + 1][0], srcB, 64);
      uint32_t b3 = (uint32_t)__shfl((int)pk[kk*2 + 1][1], srcB, 64);
      union { uint32_t w[4]; bf16x8 v; } u;
      u.w[0] = hi ? b0 : a0;
      u.w[1] = hi ? b1 : a1;
      u.w[2] = hi ? b2 : a2;
      u.w[3] = hi ? b3 : a3;
      pa[kk] = u.v;
    }

    // PV: o[dt] += pa * Vt   (D: row = q = g*4+r, col = d = dt*16+c)
    __builtin_amdgcn_s_setprio(1);
#pragma unroll
    for (int kk = 0; kk < 2; kk++) {
#pragma unroll
      for (int dt = 0; dt < 8; dt++) {
        int slot = (kk*4 + g) ^ (c & 7);
        bf16x8 vb = *reinterpret_cast<const bf16x8*>(&sV[cur][(dt*16 + c)*KVBLK + slot*8]);
        o[dt] = mfma16(pa[kk], vb, o[dt]);
      }
    }
    __builtin_amdgcn_s_setprio(0);

    __syncthreads();   // one barrier/tile: drains prefetch writes + joins readers
    cur ^= 1;
  }

  // final l reduce across g-copies, then distribute 1/l to output rows
  l_r += __shfl_xor(l_r, 16, 64);
  l_r += __shfl_xor(l_r, 32, 64);
  float inv = 1.f / l_r;
  float invq[4];
#pragma unroll
  for (int r = 0; r < 4; r++) invq[r] = __shfl(inv, g*4 + r, 64);

  u16* Aop = Ao + ((size_t)(b*T_) + q0 + wave*16) * (H_*D_) + h*D_;
#pragma unroll
  for (int dt = 0; dt < 8; dt++)
#pragma unroll
    for (int r = 0; r < 4; r++)
      Aop[(size_t)(g*4 + r)*(H_*D_) + dt*16 + c] = f2bf(o[dt][r] * invq[r]);
}

// ---------------- launch ----------------
extern "C" void kernel_launch(void* const* d_in, const int* in_sizes, int n_in,
                              void* d_out, int out_size, void* d_ws, size_t ws_size,
                              hipStream_t stream) {
  const float* x  = (const float*)d_in[0];
  const float* Wq = (const float*)d_in[1];
  const float* Wk = (const float*)d_in[2];
  const float* Wv = (const float*)d_in[3];
  const float* Wp = (const float*)d_in[4];
  float* out = (float*)d_out;
  char* ws = (char*)d_ws;

  size_t off = 0;
  auto alloc = [&](size_t bytes) { size_t o = off; off += (bytes + 255) & ~(size_t)255; return o; };
  u16*  xb  = (u16*)(ws + alloc((size_t)M_*C_*2));
  u16*  wqT = (u16*)(ws + alloc((size_t)C_*C_*2));
  u16*  wkT = (u16*)(ws + alloc((size_t)NKV_*C_*2));
  u16*  wvT = (u16*)(ws + alloc((size_t)NKV_*C_*2));
  u16*  wpT = (u16*)(ws + alloc((size_t)C_*C_*2));
  float* qf = (float*)(ws + alloc((size_t)M_*C_*4));
  float* kf = (float*)(ws + alloc((size_t)M_*NKV_*4));
  float* vf = (float*)(ws + alloc((size_t)M_*NKV_*4));
  u16*  Qb  = (u16*)(ws + alloc((size_t)M_*C_*2));
  u16*  Kb  = (u16*)(ws + alloc((size_t)M_*NKV_*2));
  u16*  Vtb = (u16*)(ws + alloc((size_t)M_*NKV_*2));
  float* cs = (float*)(ws + alloc((size_t)T_*64*4));
  float* sn = (float*)(ws + alloc((size_t)T_*64*4));
  u16*  Ao  = (u16*)qf;   // alias: qf is dead after rope_apply(q)
  // total ws footprint ~144 MB

  cvt_bf16<<<(M_*C_/4 + 255)/256, 256, 0, stream>>>(x, xb, M_*C_/4);
  wtrans<<<(C_/64)*(C_/64),   256, 0, stream>>>(Wq, wqT, C_, C_);
  wtrans<<<(C_/64)*(NKV_/64), 256, 0, stream>>>(Wk, wkT, C_, NKV_);
  wtrans<<<(C_/64)*(NKV_/64), 256, 0, stream>>>(Wv, wvT, C_, NKV_);
  wtrans<<<(C_/64)*(C_/64),   256, 0, stream>>>(Wp, wpT, C_, C_);
  rope_tab<<<(T_*64 + 255)/256, 256, 0, stream>>>(cs, sn);

  gemm_bt<<<(M_/BM)*(C_/BN),   256, 0, stream>>>(xb, wqT, qf, M_, C_, C_);
  gemm_bt<<<(M_/BM)*(NKV_/BN), 256, 0, stream>>>(xb, wkT, kf, M_, NKV_, C_);
  gemm_bt<<<(M_/BM)*(NKV_/BN), 256, 0, stream>>>(xb, wvT, vf, M_, NKV_, C_);

  rope_apply<<<(B_*T_*H_*64)/256,   256, 0, stream>>>(qf, Qb, cs, sn, H_);
  rope_apply<<<(B_*T_*HKV_*64)/256, 256, 0, stream>>>(kf, Kb, cs, sn, HKV_);
  vtrans<<<B_*HKV_*(T_/64)*(D_/64), 256, 0, stream>>>(vf, Vtb);

  attn_fwd<<<B_*H_*(T_/QBLK), 256, 0, stream>>>(Qb, Kb, Vtb, Ao);

  gemm_bt<<<(M_/BM)*(C_/BN), 256, 0, stream>>>(Ao, wpT, out, M_, C_, C_);
}

// Round 5
// 397.679 us; speedup vs baseline: 1.6025x; 1.1818x over previous
//
#include <hip/hip_runtime.h>
#include <cstdint>
#include <cstddef>
#include <type_traits>

#define B_ 2
#define T_ 2048
#define C_ 2048
#define H_ 16
#define HKV_ 8
#define D_ 128
#define M_ (B_*T_)          // 4096 tokens
#define NKV_ (HKV_*D_)      // 1024
#define QKV_N 4096          // fused q|k|v output width

typedef unsigned short u16;
typedef __bf16 bf16_t;
typedef bf16_t bf16x8 __attribute__((ext_vector_type(8)));
typedef float f32x4 __attribute__((ext_vector_type(4)));

__device__ __forceinline__ u16 f2bf(float f) {
  union { float fl; uint32_t u; } v; v.fl = f;
  uint32_t u = v.u;
  return (u16)((u + 0x7fffu + ((u >> 16) & 1u)) >> 16);  // RNE
}
__device__ __forceinline__ float bf2f(u16 h) {
  union { uint32_t u; float f; } v; v.u = ((uint32_t)h) << 16;
  return v.f;
}

__device__ __forceinline__ void gload_lds16(const void* g, void* l) {
  // async global->LDS, 16B/lane; LDS dest = wave-uniform base + lane*16
  __builtin_amdgcn_global_load_lds(
      (const __attribute__((address_space(1))) unsigned int*)g,
      (__attribute__((address_space(3))) unsigned int*)l, 16, 0, 0);
}

__device__ __forceinline__ f32x4 mfma16(bf16x8 a, bf16x8 b, f32x4 c) {
  return __builtin_amdgcn_mfma_f32_16x16x32_bf16(a, b, c, 0, 0, 0);
}

// 2x f32 -> packed bf16 pair (lo = a, hi = b). T12 recipe: no builtin on gfx950.
__device__ __forceinline__ uint32_t cvt_pk_bf16(float a, float b) {
  uint32_t r;
  asm("v_cvt_pk_bf16_f32 %0, %1, %2" : "=v"(r) : "v"(a), "v"(b));
  return r;
}

// ---------------- elementwise f32 -> bf16 ----------------
__global__ void cvt_bf16(const float* __restrict__ in, u16* __restrict__ out, int n4) {
  int i = blockIdx.x * blockDim.x + threadIdx.x;
  if (i >= n4) return;
  float4 f = reinterpret_cast<const float4*>(in)[i];
  ushort4 o;
  o.x = f2bf(f.x); o.y = f2bf(f.y); o.z = f2bf(f.z); o.w = f2bf(f.w);
  reinterpret_cast<ushort4*>(out)[i] = o;
}

// ------- tiled transpose+convert: W[K][N] f32 -> WT[N][K] bf16 -------
__global__ void wtrans(const float* __restrict__ w, u16* __restrict__ wt, int Kd, int Nd) {
  __shared__ float tile[64][65];
  int ntt = Nd >> 6;
  int nt = blockIdx.x % ntt, kt = blockIdx.x / ntt;
  int cc = threadIdx.x & 63, r0 = threadIdx.x >> 6;
#pragma unroll
  for (int i = 0; i < 16; i++) {
    int r = r0 + i*4;
    tile[r][cc] = w[(size_t)(kt*64 + r)*Nd + nt*64 + cc];
  }
  __syncthreads();
#pragma unroll
  for (int i = 0; i < 16; i++) {
    int r = r0 + i*4;
    wt[(size_t)(nt*64 + r)*Kd + kt*64 + cc] = f2bf(tile[cc][r]);
  }
}

// ---------------- RoPE cos/sin table [T][64] f32 ----------------
__global__ void rope_tab(float* __restrict__ cs, float* __restrict__ sn) {
  int idx = blockIdx.x * blockDim.x + threadIdx.x;
  if (idx >= T_*64) return;
  int i = idx & 63, t = idx >> 6;
  float inv = powf(10000.f, -(float)i / 64.f);
  float fr = (float)t * inv;
  cs[idx] = cosf(fr);
  sn[idx] = sinf(fr);
}

// ---- rope + reshape: src bf16 [B*T, QKV_N] (col offset) -> dst bf16 [B, nh, T, D] ----
__global__ void rope_apply(const u16* __restrict__ src, u16* __restrict__ dst,
                           const float* __restrict__ cs, const float* __restrict__ sn,
                           int nheads, int colOff) {
  int idx = blockIdx.x * blockDim.x + threadIdx.x;
  if (idx >= B_*T_*nheads*64) return;
  int i = idx & 63;
  int hh = (idx >> 6) % nheads;
  int bt = (idx >> 6) / nheads;
  int t = bt % T_, b = bt / T_;
  size_t sbase = (size_t)bt * QKV_N + colOff + (size_t)hh * D_;
  size_t obase = ((size_t)(b*nheads + hh) * T_ + t) * D_;
  float x1 = bf2f(src[sbase + i]), x2 = bf2f(src[sbase + 64 + i]);
  float cv = cs[t*64 + i], sv = sn[t*64 + i];
  dst[obase + i]      = f2bf(x1*cv - x2*sv);
  dst[obase + 64 + i] = f2bf(x2*cv + x1*sv);
}

// -- V: bf16 [B*T, QKV_N] (col 3072+) -> bf16 Vt [B, HKV, D, T] (transposed per head) --
__global__ void vtrans(const u16* __restrict__ v, u16* __restrict__ vt) {
  __shared__ u16 tile[64][65];
  int bid = blockIdx.x;
  int dt = bid & 1;
  int tt = (bid >> 1) & 31;
  int h  = (bid >> 6) & 7;
  int b  = bid >> 9;
  int cc = threadIdx.x & 63, r0 = threadIdx.x >> 6;
#pragma unroll
  for (int i = 0; i < 16; i++) {
    int r = r0 + i*4;
    tile[r][cc] = v[(size_t)(b*T_ + tt*64 + r)*QKV_N + 3072 + h*D_ + dt*64 + cc];
  }
  __syncthreads();
#pragma unroll
  for (int i = 0; i < 16; i++) {
    int r = r0 + i*4;  // d index within tile
    vt[((size_t)(b*HKV_ + h)*D_ + dt*64 + r)*T_ + tt*64 + cc] = tile[cc][r];
  }
}

// ---------------- GEMM: C[M][N] = A[M][K] bf16 * Bt[N][K] bf16 ----------------
// OT = float (f32 out) or u16 (bf16 out)
#define BM 128
#define BN 128
#define BK 64

template <typename OT>
__global__ __launch_bounds__(256, 2)
void gemm_bt(const u16* __restrict__ A, const u16* __restrict__ Bt,
             OT* __restrict__ Cm, int Md, int Nd, int Kd) {
  __shared__ u16 sA[BM * BK];   // [128][64]
  __shared__ u16 sB[BN * BK];   // [128][64]
  const int tid = threadIdx.x;
  const int wave = tid >> 6, lane = tid & 63;
  const int g = lane >> 4, c = lane & 15;
  const int nbn = Nd / BN;
  const int bm = blockIdx.x / nbn, bn = blockIdx.x % nbn;
  const int m0 = bm * BM, n0 = bn * BN;
  const int wm = (wave >> 1) * 64, wn = (wave & 1) * 64;
  const int srow = lane >> 3, skcol = (lane & 7) * 8;

  f32x4 acc[4][4] = {};

  for (int k0 = 0; k0 < Kd; k0 += BK) {
    __syncthreads();
#pragma unroll
    for (int i = 0; i < 4; i++) {
      int chunk = i*4 + wave;              // wave-uniform
      int row = chunk*8 + srow;
      gload_lds16(A  + (size_t)(m0 + row)*Kd + k0 + skcol, &sA[chunk*512]);
      gload_lds16(Bt + (size_t)(n0 + row)*Kd + k0 + skcol, &sB[chunk*512]);
    }
    __syncthreads();
#pragma unroll
    for (int ks = 0; ks < 2; ks++) {
      bf16x8 af[4], bb[4];
#pragma unroll
      for (int mi = 0; mi < 4; mi++)
        af[mi] = *reinterpret_cast<const bf16x8*>(&sA[(wm + mi*16 + c)*BK + ks*32 + g*8]);
#pragma unroll
      for (int ni = 0; ni < 4; ni++)
        bb[ni] = *reinterpret_cast<const bf16x8*>(&sB[(wn + ni*16 + c)*BK + ks*32 + g*8]);
#pragma unroll
      for (int mi = 0; mi < 4; mi++)
#pragma unroll
        for (int ni = 0; ni < 4; ni++)
          acc[mi][ni] = mfma16(af[mi], bb[ni], acc[mi][ni]);
    }
  }

#pragma unroll
  for (int mi = 0; mi < 4; mi++)
#pragma unroll
    for (int ni = 0; ni < 4; ni++) {
      int rb = m0 + wm + mi*16 + g*4;
      int col = n0 + wn + ni*16 + c;
#pragma unroll
      for (int r = 0; r < 4; r++) {
        if constexpr (std::is_same<OT, u16>::value)
          Cm[(size_t)(rb + r)*Nd + col] = f2bf(acc[mi][ni][r]);
        else
          Cm[(size_t)(rb + r)*Nd + col] = acc[mi][ni][r];   // C/D: row=4g+r, col=c
      }
    }
}

// ---------------- causal GQA flash attention (v4) ----------------
// Q [B,H,T,D], K [B,HKV,T,D], Vt [B,HKV,D,T] (all bf16) -> Ao [B,T,H*D] bf16
// v4: GQA head-pairing — 8 waves/block; waves 0-3 = q-head 2*hkv, waves 4-7 =
//     q-head 2*hkv+1, sharing staged K/V (halves staging + barriers + K/V HBM
//     per FLOP, doubles waves/CU). Per-wave math identical to v3 (T12/T13).
// Layout facts (HW-verified): A/B frag lane holds row/col = c, k = ks*32+8g+j;
// C/D: row = g*4+r, col = c.
#define QBLK 64
#define KVBLK 64

__global__ __launch_bounds__(512, 4)
void attn_fwd(const u16* __restrict__ Q, const u16* __restrict__ K,
              const u16* __restrict__ Vt, u16* __restrict__ Ao) {
  __shared__ u16 sK[2][KVBLK * D_];   // [64 kv][128 d], slot^=(row&7) swizzle
  __shared__ u16 sV[2][D_ * KVBLK];   // [128 d][64 kv], slot^=(row&7) swizzle
  const int tid = threadIdx.x;
  const int wave = tid >> 6, lane = tid & 63;
  const int wq = wave & 3;            // q-subtile within head
  const int hsel = wave >> 2;         // which q-head of the GQA pair
  const int g = lane >> 4, c = lane & 15;
  const int bid = blockIdx.x;
  const int qt = 31 - (bid & 31);     // reversed: big blocks first
  const int hkv = (bid >> 5) & 7;
  const int b  = bid >> 8;
  const int h  = hkv*2 + hsel;
  const int q0 = qt * QBLK;

  const u16* Qp = Q  + ((size_t)(b*H_ + h)*T_ + q0 + wq*16) * D_;
  const u16* Kp = K  + (size_t)(b*HKV_ + hkv) * T_ * D_;
  const u16* Vp = Vt + (size_t)(b*HKV_ + hkv) * D_ * T_;

  bf16x8 qf[4];
#pragma unroll
  for (int ks = 0; ks < 4; ks++)      // frag: row=c, k = ks*32 + 8g + j
    qf[ks] = *reinterpret_cast<const bf16x8*>(Qp + (size_t)c*D_ + ks*32 + g*8);

  f32x4 o[8] = {};
  float m_r = -1e30f, l_r = 0.f;      // per-lane: q = q0 + wq*16 + c

  const float scale = 0.08838834764831845f;  // 1/sqrt(128)
  const int ntiles = qt + 1;
  const int qglob = q0 + wq*16 + c;

  // stage tile t into buffer bsel (8 waves, 16 chunks of 1KB each for K and V)
  auto stage = [&](int t, int bsel) {
    const int kv0 = t * KVBLK;
#pragma unroll
    for (int i = 0; i < 2; i++) {
      int chunk = i*8 + wave;                   // wave-uniform
      int kr = chunk*4 + (lane >> 4);           // 0..63
      int kslot = (lane & 15) ^ (kr & 7);
      gload_lds16(Kp + (size_t)(kv0 + kr)*D_ + kslot*8, &sK[bsel][chunk*512]);
      int vr = chunk*8 + (lane >> 3);           // 0..127
      int vslot = (lane & 7) ^ (vr & 7);
      gload_lds16(Vp + (size_t)vr*T_ + kv0 + vslot*8, &sV[bsel][chunk*512]);
    }
  };

  stage(0, 0);
  __syncthreads();                              // drains vmcnt

  int cur = 0;
  for (int t = 0; t < ntiles; t++) {
    const int kv0 = t * KVBLK;
    if (t + 1 < ntiles) stage(t + 1, cur ^ 1);  // prefetch, overlaps compute

    // Swapped QK^T: st[nf] = S[kv = kv0+nf*16+g*4+r][q = qglob]
    f32x4 st[4] = {};
    __builtin_amdgcn_s_setprio(1);
#pragma unroll
    for (int ks = 0; ks < 4; ks++) {
#pragma unroll
      for (int nf = 0; nf < 4; nf++) {
        int slot = (ks*4 + g) ^ (c & 7);
        bf16x8 kb = *reinterpret_cast<const bf16x8*>(&sK[cur][(nf*16 + c)*D_ + slot*8]);
        st[nf] = mfma16(kb, qf[ks], st[nf]);    // A=K (M=kv), B=Q (N=q)
      }
    }
    __builtin_amdgcn_s_setprio(0);

    // scale + causal mask (kv > q)
    float p[4][4];
    const bool maskt = (t == ntiles - 1);
#pragma unroll
    for (int nf = 0; nf < 4; nf++)
#pragma unroll
      for (int r = 0; r < 4; r++) {
        float s = st[nf][r] * scale;
        if (maskt && (kv0 + nf*16 + g*4 + r > qglob)) s = -1e30f;
        p[nf][r] = s;
      }

    // row max: per-lane tree over 16, then cross-g (lanes +-16, +-32)
    float mx0 = fmaxf(fmaxf(p[0][0], p[0][1]), fmaxf(p[0][2], p[0][3]));
    float mx1 = fmaxf(fmaxf(p[1][0], p[1][1]), fmaxf(p[1][2], p[1][3]));
    float mx2 = fmaxf(fmaxf(p[2][0], p[2][1]), fmaxf(p[2][2], p[2][3]));
    float mx3 = fmaxf(fmaxf(p[3][0], p[3][1]), fmaxf(p[3][2], p[3][3]));
    float mx = fmaxf(fmaxf(mx0, mx1), fmaxf(mx2, mx3));
    mx = fmaxf(mx, __shfl_xor(mx, 16, 64));
    mx = fmaxf(mx, __shfl_xor(mx, 32, 64));

    // defer-max (T13): only rescale when max grew past THR=8
    if (!__all(mx <= m_r + 8.f)) {
      float mn = fmaxf(m_r, mx);
      float alpha = __expf(m_r - mn);
      m_r = mn;
      l_r *= alpha;
      float aq[4];
#pragma unroll
      for (int r = 0; r < 4; r++) aq[r] = __shfl(alpha, g*4 + r, 64);
#pragma unroll
      for (int dt = 0; dt < 8; dt++)
#pragma unroll
        for (int r = 0; r < 4; r++) o[dt][r] *= aq[r];
    }

    // exp + per-lane partial sum (pairwise)
#pragma unroll
    for (int nf = 0; nf < 4; nf++)
#pragma unroll
      for (int r = 0; r < 4; r++) p[nf][r] = __expf(p[nf][r] - m_r);
    float s0 = (p[0][0] + p[0][1]) + (p[0][2] + p[0][3]);
    float s1 = (p[1][0] + p[1][1]) + (p[1][2] + p[1][3]);
    float s2 = (p[2][0] + p[2][1]) + (p[2][2] + p[2][3]);
    float s3 = (p[3][0] + p[3][1]) + (p[3][2] + p[3][3]);
    l_r += (s0 + s1) + (s2 + s3);

    // pack: pk[nf][w] = bf16 pair for kv = nf*16 + g*4 + 2w (lo), +1 (hi)
    uint32_t pk[4][2];
#pragma unroll
    for (int nf = 0; nf < 4; nf++) {
      pk[nf][0] = cvt_pk_bf16(p[nf][0], p[nf][1]);
      pk[nf][1] = cvt_pk_bf16(p[nf][2], p[nf][3]);
    }

    // redistribute to PV A-frag: pa[kk] elem j = P[q=c][kv = kk*32 + g*8 + j]
    // word t (t=0..3) = pk[kk*2 + (g>>1)][t&1] from lane ((2g + (t>>1))&3)*16 + c
    const int srcA = (((2*g)     & 3) << 4) | c;
    const int srcB = (((2*g + 1) & 3) << 4) | c;
    const bool hi = (g >> 1);
    bf16x8 pa[2];
#pragma unroll
    for (int kk = 0; kk < 2; kk++) {
      uint32_t a0 = (uint32_t)__shfl((int)pk[kk*2    ][0], srcA, 64);
      uint32_t a1 = (uint32_t)__shfl((int)pk[kk*2    ][1], srcA, 64);
      uint32_t b0 = (uint32_t)__shfl((int)pk[kk*2 + 1][0], srcA, 64);
      uint32_t b1 = (uint32_t)__shfl((int)pk[kk*2 + 1][1], srcA, 64);
      uint32_t a2 = (uint32_t)__shfl((int)pk[kk*2    ][0], srcB, 64);
      uint32_t a3 = (uint32_t)__shfl((int)pk[kk*2    ][1], srcB, 64);
      uint32_t b2 = (uint32_t)__shfl((int)pk[kk*2 + 1][0], srcB, 64);
      uint32_t b3 = (uint32_t)__shfl((int)pk[kk*2 + 1][1], srcB, 64);
      union { uint32_t w[4]; bf16x8 v; } u;
      u.w[0] = hi ? b0 : a0;
      u.w[1] = hi ? b1 : a1;
      u.w[2] = hi ? b2 : a2;
      u.w[3] = hi ? b3 : a3;
      pa[kk] = u.v;
    }

    // PV: o[dt] += pa * Vt   (D: row = q = g*4+r, col = d = dt*16+c)
    __builtin_amdgcn_s_setprio(1);
#pragma unroll
    for (int kk = 0; kk < 2; kk++) {
#pragma unroll
      for (int dt = 0; dt < 8; dt++) {
        int slot = (kk*4 + g) ^ (c & 7);
        bf16x8 vb = *reinterpret_cast<const bf16x8*>(&sV[cur][(dt*16 + c)*KVBLK + slot*8]);
        o[dt] = mfma16(pa[kk], vb, o[dt]);
      }
    }
    __builtin_amdgcn_s_setprio(0);

    __syncthreads();   // one barrier/tile: drains prefetch writes + joins readers
    cur ^= 1;
  }

  // final l reduce across g-copies, then distribute 1/l to output rows
  l_r += __shfl_xor(l_r, 16, 64);
  l_r += __shfl_xor(l_r, 32, 64);
  float inv = 1.f / l_r;
  float invq[4];
#pragma unroll
  for (int r = 0; r < 4; r++) invq[r] = __shfl(inv, g*4 + r, 64);

  u16* Aop = Ao + ((size_t)(b*T_) + q0 + wq*16) * (H_*D_) + h*D_;
#pragma unroll
  for (int dt = 0; dt < 8; dt++)
#pragma unroll
    for (int r = 0; r < 4; r++)
      Aop[(size_t)(g*4 + r)*(H_*D_) + dt*16 + c] = f2bf(o[dt][r] * invq[r]);
}

// ---------------- launch ----------------
extern "C" void kernel_launch(void* const* d_in, const int* in_sizes, int n_in,
                              void* d_out, int out_size, void* d_ws, size_t ws_size,
                              hipStream_t stream) {
  const float* x  = (const float*)d_in[0];
  const float* Wq = (const float*)d_in[1];
  const float* Wk = (const float*)d_in[2];
  const float* Wv = (const float*)d_in[3];
  const float* Wp = (const float*)d_in[4];
  float* out = (float*)d_out;
  char* ws = (char*)d_ws;

  size_t off = 0;
  auto alloc = [&](size_t bytes) { size_t o = off; off += (bytes + 255) & ~(size_t)255; return o; };
  u16*  xb  = (u16*)(ws + alloc((size_t)M_*C_*2));
  // wqT/wkT/wvT MUST stay contiguous (fused QKV Bt [4096][2048]); sizes are
  // multiples of 256B so alloc() introduces no gaps.
  u16*  wqT = (u16*)(ws + alloc((size_t)C_*C_*2));
  u16*  wkT = (u16*)(ws + alloc((size_t)NKV_*C_*2));
  u16*  wvT = (u16*)(ws + alloc((size_t)NKV_*C_*2));
  u16*  wpT = (u16*)(ws + alloc((size_t)C_*C_*2));
  u16*  qkvb= (u16*)(ws + alloc((size_t)M_*QKV_N*2));   // fused bf16 [M][4096]
  u16*  Qb  = (u16*)(ws + alloc((size_t)M_*C_*2));
  u16*  Kb  = (u16*)(ws + alloc((size_t)M_*NKV_*2));
  u16*  Vtb = (u16*)(ws + alloc((size_t)M_*NKV_*2));
  float* cs = (float*)(ws + alloc((size_t)T_*64*4));
  float* sn = (float*)(ws + alloc((size_t)T_*64*4));
  u16*  Ao  = qkvb;   // alias: qkvb dead after rope_apply/vtrans consume it

  cvt_bf16<<<(M_*C_/4 + 255)/256, 256, 0, stream>>>(x, xb, M_*C_/4);
  wtrans<<<(C_/64)*(C_/64),   256, 0, stream>>>(Wq, wqT, C_, C_);
  wtrans<<<(C_/64)*(NKV_/64), 256, 0, stream>>>(Wk, wkT, C_, NKV_);
  wtrans<<<(C_/64)*(NKV_/64), 256, 0, stream>>>(Wv, wvT, C_, NKV_);
  wtrans<<<(C_/64)*(C_/64),   256, 0, stream>>>(Wp, wpT, C_, C_);
  rope_tab<<<(T_*64 + 255)/256, 256, 0, stream>>>(cs, sn);

  // fused QKV projection: [M][2048] x [4096][2048]^T -> bf16 [M][4096]
  gemm_bt<u16><<<(M_/BM)*(QKV_N/BN), 256, 0, stream>>>(xb, wqT, qkvb, M_, QKV_N, C_);

  rope_apply<<<(B_*T_*H_*64)/256,   256, 0, stream>>>(qkvb, Qb, cs, sn, H_, 0);
  rope_apply<<<(B_*T_*HKV_*64)/256, 256, 0, stream>>>(qkvb, Kb, cs, sn, HKV_, 2048);
  vtrans<<<B_*HKV_*(T_/64)*(D_/64), 256, 0, stream>>>(qkvb, Vtb);

  attn_fwd<<<B_*HKV_*(T_/QBLK), 512, 0, stream>>>(Qb, Kb, Vtb, Ao);

  gemm_bt<float><<<(M_/BM)*(C_/BN), 256, 0, stream>>>(Ao, wpT, out, M_, C_, C_);
}

// Round 8
// 364.675 us; speedup vs baseline: 1.7475x; 1.0905x over previous
//
#include <hip/hip_runtime.h>
#include <cstdint>
#include <cstddef>
#include <type_traits>

#define B_ 2
#define T_ 2048
#define C_ 2048
#define H_ 16
#define HKV_ 8
#define D_ 128
#define M_ (B_*T_)          // 4096 tokens
#define NKV_ (HKV_*D_)      // 1024
#define QKV_N 4096          // fused q|k|v output width

typedef unsigned short u16;
typedef __bf16 bf16_t;
typedef bf16_t bf16x8 __attribute__((ext_vector_type(8)));
typedef float f32x4 __attribute__((ext_vector_type(4)));

__device__ __forceinline__ u16 f2bf(float f) {
  union { float fl; uint32_t u; } v; v.fl = f;
  uint32_t u = v.u;
  return (u16)((u + 0x7fffu + ((u >> 16) & 1u)) >> 16);  // RNE
}
__device__ __forceinline__ float bf2f(u16 h) {
  union { uint32_t u; float f; } v; v.u = ((uint32_t)h) << 16;
  return v.f;
}

__device__ __forceinline__ void gload_lds16(const void* g, void* l) {
  // async global->LDS, 16B/lane; LDS dest = wave-uniform base + lane*16
  __builtin_amdgcn_global_load_lds(
      (const __attribute__((address_space(1))) unsigned int*)g,
      (__attribute__((address_space(3))) unsigned int*)l, 16, 0, 0);
}

__device__ __forceinline__ f32x4 mfma16(bf16x8 a, bf16x8 b, f32x4 c) {
  return __builtin_amdgcn_mfma_f32_16x16x32_bf16(a, b, c, 0, 0, 0);
}

// 2x f32 -> packed bf16 pair (lo = a, hi = b). T12 recipe: no builtin on gfx950.
__device__ __forceinline__ uint32_t cvt_pk_bf16(float a, float b) {
  uint32_t r;
  asm("v_cvt_pk_bf16_f32 %0, %1, %2" : "=v"(r) : "v"(a), "v"(b));
  return r;
}

// ---------------- elementwise f32 -> bf16 ----------------
__global__ void cvt_bf16(const float* __restrict__ in, u16* __restrict__ out, int n4) {
  int i = blockIdx.x * blockDim.x + threadIdx.x;
  if (i >= n4) return;
  float4 f = reinterpret_cast<const float4*>(in)[i];
  ushort4 o;
  o.x = f2bf(f.x); o.y = f2bf(f.y); o.z = f2bf(f.z); o.w = f2bf(f.w);
  reinterpret_cast<ushort4*>(out)[i] = o;
}

// ------- tiled transpose+convert: W[K][N] f32 -> WT[N][K] bf16 -------
__global__ void wtrans(const float* __restrict__ w, u16* __restrict__ wt, int Kd, int Nd) {
  __shared__ float tile[64][65];
  int ntt = Nd >> 6;
  int nt = blockIdx.x % ntt, kt = blockIdx.x / ntt;
  int cc = threadIdx.x & 63, r0 = threadIdx.x >> 6;
#pragma unroll
  for (int i = 0; i < 16; i++) {
    int r = r0 + i*4;
    tile[r][cc] = w[(size_t)(kt*64 + r)*Nd + nt*64 + cc];
  }
  __syncthreads();
#pragma unroll
  for (int i = 0; i < 16; i++) {
    int r = r0 + i*4;
    wt[(size_t)(nt*64 + r)*Kd + kt*64 + cc] = f2bf(tile[cc][r]);
  }
}

// ---------------- RoPE cos/sin table [T][64] f32 ----------------
__global__ void rope_tab(float* __restrict__ cs, float* __restrict__ sn) {
  int idx = blockIdx.x * blockDim.x + threadIdx.x;
  if (idx >= T_*64) return;
  int i = idx & 63, t = idx >> 6;
  float inv = powf(10000.f, -(float)i / 64.f);
  float fr = (float)t * inv;
  cs[idx] = cosf(fr);
  sn[idx] = sinf(fr);
}

// ---- rope + reshape: src bf16 [B*T, QKV_N] (col offset) -> dst bf16 [B, nh, T, D] ----
__global__ void rope_apply(const u16* __restrict__ src, u16* __restrict__ dst,
                           const float* __restrict__ cs, const float* __restrict__ sn,
                           int nheads, int colOff) {
  int idx = blockIdx.x * blockDim.x + threadIdx.x;
  if (idx >= B_*T_*nheads*64) return;
  int i = idx & 63;
  int hh = (idx >> 6) % nheads;
  int bt = (idx >> 6) / nheads;
  int t = bt % T_, b = bt / T_;
  size_t sbase = (size_t)bt * QKV_N + colOff + (size_t)hh * D_;
  size_t obase = ((size_t)(b*nheads + hh) * T_ + t) * D_;
  float x1 = bf2f(src[sbase + i]), x2 = bf2f(src[sbase + 64 + i]);
  float cv = cs[t*64 + i], sv = sn[t*64 + i];
  dst[obase + i]      = f2bf(x1*cv - x2*sv);
  dst[obase + 64 + i] = f2bf(x2*cv + x1*sv);
}

// -- V: bf16 [B*T, QKV_N] (col 3072+) -> bf16 Vt [B, HKV, D, T] (transposed per head) --
__global__ void vtrans(const u16* __restrict__ v, u16* __restrict__ vt) {
  __shared__ u16 tile[64][65];
  int bid = blockIdx.x;
  int dt = bid & 1;
  int tt = (bid >> 1) & 31;
  int h  = (bid >> 6) & 7;
  int b  = bid >> 9;
  int cc = threadIdx.x & 63, r0 = threadIdx.x >> 6;
#pragma unroll
  for (int i = 0; i < 16; i++) {
    int r = r0 + i*4;
    tile[r][cc] = v[(size_t)(b*T_ + tt*64 + r)*QKV_N + 3072 + h*D_ + dt*64 + cc];
  }
  __syncthreads();
#pragma unroll
  for (int i = 0; i < 16; i++) {
    int r = r0 + i*4;  // d index within tile
    vt[((size_t)(b*HKV_ + h)*D_ + dt*64 + r)*T_ + tt*64 + cc] = tile[cc][r];
  }
}

// ---------------- GEMM: C[M][N] = A[M][K] bf16 * Bt[N][K] bf16 ----------------
// OT = float (f32 out) or u16 (bf16 out)
#define BM 128
#define BN 128
#define BK 64

template <typename OT>
__global__ __launch_bounds__(256, 2)
void gemm_bt(const u16* __restrict__ A, const u16* __restrict__ Bt,
             OT* __restrict__ Cm, int Md, int Nd, int Kd) {
  __shared__ u16 sA[BM * BK];   // [128][64]
  __shared__ u16 sB[BN * BK];   // [128][64]
  const int tid = threadIdx.x;
  const int wave = tid >> 6, lane = tid & 63;
  const int g = lane >> 4, c = lane & 15;
  const int nbn = Nd / BN;
  const int bm = blockIdx.x / nbn, bn = blockIdx.x % nbn;
  const int m0 = bm * BM, n0 = bn * BN;
  const int wm = (wave >> 1) * 64, wn = (wave & 1) * 64;
  const int srow = lane >> 3, skcol = (lane & 7) * 8;

  f32x4 acc[4][4] = {};

  for (int k0 = 0; k0 < Kd; k0 += BK) {
    __syncthreads();
#pragma unroll
    for (int i = 0; i < 4; i++) {
      int chunk = i*4 + wave;              // wave-uniform
      int row = chunk*8 + srow;
      gload_lds16(A  + (size_t)(m0 + row)*Kd + k0 + skcol, &sA[chunk*512]);
      gload_lds16(Bt + (size_t)(n0 + row)*Kd + k0 + skcol, &sB[chunk*512]);
    }
    __syncthreads();
#pragma unroll
    for (int ks = 0; ks < 2; ks++) {
      bf16x8 af[4], bb[4];
#pragma unroll
      for (int mi = 0; mi < 4; mi++)
        af[mi] = *reinterpret_cast<const bf16x8*>(&sA[(wm + mi*16 + c)*BK + ks*32 + g*8]);
#pragma unroll
      for (int ni = 0; ni < 4; ni++)
        bb[ni] = *reinterpret_cast<const bf16x8*>(&sB[(wn + ni*16 + c)*BK + ks*32 + g*8]);
#pragma unroll
      for (int mi = 0; mi < 4; mi++)
#pragma unroll
        for (int ni = 0; ni < 4; ni++)
          acc[mi][ni] = mfma16(af[mi], bb[ni], acc[mi][ni]);
    }
  }

#pragma unroll
  for (int mi = 0; mi < 4; mi++)
#pragma unroll
    for (int ni = 0; ni < 4; ni++) {
      int rb = m0 + wm + mi*16 + g*4;
      int col = n0 + wn + ni*16 + c;
#pragma unroll
      for (int r = 0; r < 4; r++) {
        if constexpr (std::is_same<OT, u16>::value)
          Cm[(size_t)(rb + r)*Nd + col] = f2bf(acc[mi][ni][r]);
        else
          Cm[(size_t)(rb + r)*Nd + col] = acc[mi][ni][r];   // C/D: row=4g+r, col=c
      }
    }
}

// ---------------- causal GQA flash attention (v4.1) ----------------
// Q [B,H,T,D], K [B,HKV,T,D], Vt [B,HKV,D,T] (all bf16) -> Ao [B,T,H*D] bf16
// v4.1: EXACT round-5 kernel (proven 111us) with ONE change: complementary qt
//   mapping. bid and bid+256 co-reside on a CU; giving them depths p and 31-p
//   makes per-CU work uniform (33 tile-units vs worst-case 64).
//   (v5's in-block pairing rewrite failed numerically — reverted, see journal.)
// Layout facts (HW-verified): A/B frag lane holds row/col = c, k = ks*32+8g+j;
// C/D: row = g*4+r, col = c.
#define QBLK 64
#define KVBLK 64

__global__ __launch_bounds__(512, 4)
void attn_fwd(const u16* __restrict__ Q, const u16* __restrict__ K,
              const u16* __restrict__ Vt, u16* __restrict__ Ao) {
  __shared__ u16 sK[2][KVBLK * D_];   // [64 kv][128 d], slot^=(row&7) swizzle
  __shared__ u16 sV[2][D_ * KVBLK];   // [128 d][64 kv], slot^=(row&7) swizzle
  const int tid = threadIdx.x;
  const int wave = tid >> 6, lane = tid & 63;
  const int wq = wave & 3;            // q-subtile within head
  const int hsel = wave >> 2;         // which q-head of the GQA pair
  const int g = lane >> 4, c = lane & 15;
  const int bid = blockIdx.x;
  // complementary depth pairing: blocks bid and bid+256 share a CU; one gets
  // depth p, the other 31-p -> per-CU total constant.
  const int qt = (bid >> 8) ? (31 - (bid & 31)) : (bid & 31);
  const int hkv = (bid >> 5) & 7;
  const int b  = bid >> 8;
  const int h  = hkv*2 + hsel;
  const int q0 = qt * QBLK;

  const u16* Qp = Q  + ((size_t)(b*H_ + h)*T_ + q0 + wq*16) * D_;
  const u16* Kp = K  + (size_t)(b*HKV_ + hkv) * T_ * D_;
  const u16* Vp = Vt + (size_t)(b*HKV_ + hkv) * D_ * T_;

  bf16x8 qf[4];
#pragma unroll
  for (int ks = 0; ks < 4; ks++)      // frag: row=c, k = ks*32 + 8g + j
    qf[ks] = *reinterpret_cast<const bf16x8*>(Qp + (size_t)c*D_ + ks*32 + g*8);

  f32x4 o[8] = {};
  float m_r = -1e30f, l_r = 0.f;      // per-lane: q = q0 + wq*16 + c

  const float scale = 0.08838834764831845f;  // 1/sqrt(128)
  const int ntiles = qt + 1;
  const int qglob = q0 + wq*16 + c;

  // stage tile t into buffer bsel (8 waves, 16 chunks of 1KB each for K and V)
  auto stage = [&](int t, int bsel) {
    const int kv0 = t * KVBLK;
#pragma unroll
    for (int i = 0; i < 2; i++) {
      int chunk = i*8 + wave;                   // wave-uniform
      int kr = chunk*4 + (lane >> 4);           // 0..63
      int kslot = (lane & 15) ^ (kr & 7);
      gload_lds16(Kp + (size_t)(kv0 + kr)*D_ + kslot*8, &sK[bsel][chunk*512]);
      int vr = chunk*8 + (lane >> 3);           // 0..127
      int vslot = (lane & 7) ^ (vr & 7);
      gload_lds16(Vp + (size_t)vr*T_ + kv0 + vslot*8, &sV[bsel][chunk*512]);
    }
  };

  stage(0, 0);
  __syncthreads();                              // drains vmcnt

  int cur = 0;
  for (int t = 0; t < ntiles; t++) {
    const int kv0 = t * KVBLK;
    if (t + 1 < ntiles) stage(t + 1, cur ^ 1);  // prefetch, overlaps compute

    // Swapped QK^T: st[nf] = S[kv = kv0+nf*16+g*4+r][q = qglob]
    f32x4 st[4] = {};
    __builtin_amdgcn_s_setprio(1);
#pragma unroll
    for (int ks = 0; ks < 4; ks++) {
#pragma unroll
      for (int nf = 0; nf < 4; nf++) {
        int slot = (ks*4 + g) ^ (c & 7);
        bf16x8 kb = *reinterpret_cast<const bf16x8*>(&sK[cur][(nf*16 + c)*D_ + slot*8]);
        st[nf] = mfma16(kb, qf[ks], st[nf]);    // A=K (M=kv), B=Q (N=q)
      }
    }
    __builtin_amdgcn_s_setprio(0);

    // scale + causal mask (kv > q)
    float p[4][4];
    const bool maskt = (t == ntiles - 1);
#pragma unroll
    for (int nf = 0; nf < 4; nf++)
#pragma unroll
      for (int r = 0; r < 4; r++) {
        float s = st[nf][r] * scale;
        if (maskt && (kv0 + nf*16 + g*4 + r > qglob)) s = -1e30f;
        p[nf][r] = s;
      }

    // row max: per-lane tree over 16, then cross-g (lanes +-16, +-32)
    float mx0 = fmaxf(fmaxf(p[0][0], p[0][1]), fmaxf(p[0][2], p[0][3]));
    float mx1 = fmaxf(fmaxf(p[1][0], p[1][1]), fmaxf(p[1][2], p[1][3]));
    float mx2 = fmaxf(fmaxf(p[2][0], p[2][1]), fmaxf(p[2][2], p[2][3]));
    float mx3 = fmaxf(fmaxf(p[3][0], p[3][1]), fmaxf(p[3][2], p[3][3]));
    float mx = fmaxf(fmaxf(mx0, mx1), fmaxf(mx2, mx3));
    mx = fmaxf(mx, __shfl_xor(mx, 16, 64));
    mx = fmaxf(mx, __shfl_xor(mx, 32, 64));

    // defer-max (T13): only rescale when max grew past THR=8
    if (!__all(mx <= m_r + 8.f)) {
      float mn = fmaxf(m_r, mx);
      float alpha = __expf(m_r - mn);
      m_r = mn;
      l_r *= alpha;
      float aq[4];
#pragma unroll
      for (int r = 0; r < 4; r++) aq[r] = __shfl(alpha, g*4 + r, 64);
#pragma unroll
      for (int dt = 0; dt < 8; dt++)
#pragma unroll
        for (int r = 0; r < 4; r++) o[dt][r] *= aq[r];
    }

    // exp + per-lane partial sum (pairwise)
#pragma unroll
    for (int nf = 0; nf < 4; nf++)
#pragma unroll
      for (int r = 0; r < 4; r++) p[nf][r] = __expf(p[nf][r] - m_r);
    float s0 = (p[0][0] + p[0][1]) + (p[0][2] + p[0][3]);
    float s1 = (p[1][0] + p[1][1]) + (p[1][2] + p[1][3]);
    float s2 = (p[2][0] + p[2][1]) + (p[2][2] + p[2][3]);
    float s3 = (p[3][0] + p[3][1]) + (p[3][2] + p[3][3]);
    l_r += (s0 + s1) + (s2 + s3);

    // pack: pk[nf][w] = bf16 pair for kv = nf*16 + g*4 + 2w (lo), +1 (hi)
    uint32_t pk[4][2];
#pragma unroll
    for (int nf = 0; nf < 4; nf++) {
      pk[nf][0] = cvt_pk_bf16(p[nf][0], p[nf][1]);
      pk[nf][1] = cvt_pk_bf16(p[nf][2], p[nf][3]);
    }

    // redistribute to PV A-frag: pa[kk] elem j = P[q=c][kv = kk*32 + g*8 + j]
    // word t (t=0..3) = pk[kk*2 + (g>>1)][t&1] from lane ((2g + (t>>1))&3)*16 + c
    const int srcA = (((2*g)     & 3) << 4) | c;
    const int srcB = (((2*g + 1) & 3) << 4) | c;
    const bool hi = (g >> 1);
    bf16x8 pa[2];
#pragma unroll
    for (int kk = 0; kk < 2; kk++) {
      uint32_t a0 = (uint32_t)__shfl((int)pk[kk*2    ][0], srcA, 64);
      uint32_t a1 = (uint32_t)__shfl((int)pk[kk*2    ][1], srcA, 64);
      uint32_t b0 = (uint32_t)__shfl((int)pk[kk*2 + 1][0], srcA, 64);
      uint32_t b1 = (uint32_t)__shfl((int)pk[kk*2 + 1][1], srcA, 64);
      uint32_t a2 = (uint32_t)__shfl((int)pk[kk*2    ][0], srcB, 64);
      uint32_t a3 = (uint32_t)__shfl((int)pk[kk*2    ][1], srcB, 64);
      uint32_t b2 = (uint32_t)__shfl((int)pk[kk*2 + 1][0], srcB, 64);
      uint32_t b3 = (uint32_t)__shfl((int)pk[kk*2 + 1][1], srcB, 64);
      union { uint32_t w[4]; bf16x8 v; } u;
      u.w[0] = hi ? b0 : a0;
      u.w[1] = hi ? b1 : a1;
      u.w[2] = hi ? b2 : a2;
      u.w[3] = hi ? b3 : a3;
      pa[kk] = u.v;
    }

    // PV: o[dt] += pa * Vt   (D: row = q = g*4+r, col = d = dt*16+c)
    __builtin_amdgcn_s_setprio(1);
#pragma unroll
    for (int kk = 0; kk < 2; kk++) {
#pragma unroll
      for (int dt = 0; dt < 8; dt++) {
        int slot = (kk*4 + g) ^ (c & 7);
        bf16x8 vb = *reinterpret_cast<const bf16x8*>(&sV[cur][(dt*16 + c)*KVBLK + slot*8]);
        o[dt] = mfma16(pa[kk], vb, o[dt]);
      }
    }
    __builtin_amdgcn_s_setprio(0);

    __syncthreads();   // one barrier/tile: drains prefetch writes + joins readers
    cur ^= 1;
  }

  // final l reduce across g-copies, then distribute 1/l to output rows
  l_r += __shfl_xor(l_r, 16, 64);
  l_r += __shfl_xor(l_r, 32, 64);
  float inv = 1.f / l_r;
  float invq[4];
#pragma unroll
  for (int r = 0; r < 4; r++) invq[r] = __shfl(inv, g*4 + r, 64);

  u16* Aop = Ao + ((size_t)(b*T_) + q0 + wq*16) * (H_*D_) + h*D_;
#pragma unroll
  for (int dt = 0; dt < 8; dt++)
#pragma unroll
    for (int r = 0; r < 4; r++)
      Aop[(size_t)(g*4 + r)*(H_*D_) + dt*16 + c] = f2bf(o[dt][r] * invq[r]);
}

// ---------------- launch ----------------
extern "C" void kernel_launch(void* const* d_in, const int* in_sizes, int n_in,
                              void* d_out, int out_size, void* d_ws, size_t ws_size,
                              hipStream_t stream) {
  const float* x  = (const float*)d_in[0];
  const float* Wq = (const float*)d_in[1];
  const float* Wk = (const float*)d_in[2];
  const float* Wv = (const float*)d_in[3];
  const float* Wp = (const float*)d_in[4];
  float* out = (float*)d_out;
  char* ws = (char*)d_ws;

  size_t off = 0;
  auto alloc = [&](size_t bytes) { size_t o = off; off += (bytes + 255) & ~(size_t)255; return o; };
  u16*  xb  = (u16*)(ws + alloc((size_t)M_*C_*2));
  // wqT/wkT/wvT MUST stay contiguous (fused QKV Bt [4096][2048]); sizes are
  // multiples of 256B so alloc() introduces no gaps.
  u16*  wqT = (u16*)(ws + alloc((size_t)C_*C_*2));
  u16*  wkT = (u16*)(ws + alloc((size_t)NKV_*C_*2));
  u16*  wvT = (u16*)(ws + alloc((size_t)NKV_*C_*2));
  u16*  wpT = (u16*)(ws + alloc((size_t)C_*C_*2));
  u16*  qkvb= (u16*)(ws + alloc((size_t)M_*QKV_N*2));   // fused bf16 [M][4096]
  u16*  Qb  = (u16*)(ws + alloc((size_t)M_*C_*2));
  u16*  Kb  = (u16*)(ws + alloc((size_t)M_*NKV_*2));
  u16*  Vtb = (u16*)(ws + alloc((size_t)M_*NKV_*2));
  float* cs = (float*)(ws + alloc((size_t)T_*64*4));
  float* sn = (float*)(ws + alloc((size_t)T_*64*4));
  u16*  Ao  = qkvb;   // alias: qkvb dead after rope_apply/vtrans consume it

  cvt_bf16<<<(M_*C_/4 + 255)/256, 256, 0, stream>>>(x, xb, M_*C_/4);
  wtrans<<<(C_/64)*(C_/64),   256, 0, stream>>>(Wq, wqT, C_, C_);
  wtrans<<<(C_/64)*(NKV_/64), 256, 0, stream>>>(Wk, wkT, C_, NKV_);
  wtrans<<<(C_/64)*(NKV_/64), 256, 0, stream>>>(Wv, wvT, C_, NKV_);
  wtrans<<<(C_/64)*(C_/64),   256, 0, stream>>>(Wp, wpT, C_, C_);
  rope_tab<<<(T_*64 + 255)/256, 256, 0, stream>>>(cs, sn);

  // fused QKV projection: [M][2048] x [4096][2048]^T -> bf16 [M][4096]
  gemm_bt<u16><<<(M_/BM)*(QKV_N/BN), 256, 0, stream>>>(xb, wqT, qkvb, M_, QKV_N, C_);

  rope_apply<<<(B_*T_*H_*64)/256,   256, 0, stream>>>(qkvb, Qb, cs, sn, H_, 0);
  rope_apply<<<(B_*T_*HKV_*64)/256, 256, 0, stream>>>(qkvb, Kb, cs, sn, HKV_, 2048);
  vtrans<<<B_*HKV_*(T_/64)*(D_/64), 256, 0, stream>>>(qkvb, Vtb);

  attn_fwd<<<B_*HKV_*32, 512, 0, stream>>>(Qb, Kb, Vtb, Ao);

  gemm_bt<float><<<(M_/BM)*(C_/BN), 256, 0, stream>>>(Ao, wpT, out, M_, C_, C_);
}